// Round 9
// baseline (865.254 us; speedup 1.0000x reference)
//
#include <hip/hip_runtime.h>
#include <cstdint>
#include <cstddef>

// ---------------- problem constants ----------------
constexpr int B_   = 16;
constexpr int L_   = 1024;
constexpr int E_   = 192;
constexpr int DM   = 196;   // D_MODEL
constexpr int DI   = 392;   // D_INNER
constexpr int DS   = 16;    // D_STATE
constexpr int DTR  = 13;    // DT_RANK
constexpr int NTOK = B_ * L_;            // 16384
constexpr int XDW  = DTR + 2 * DS;       // 45
constexpr int CH   = B_ * DI;            // 6272 chains per direction

constexpr int KP_XZ = 224;   // 196 padded to %32
constexpr int KP_OP = 416;   // 392 padded to %32
constexpr int KP_PW = 192;

constexpr size_t HW_SZ = (size_t)NTOK * DM;   // 3,211,264
constexpr size_t DI_SZ = (size_t)NTOK * DI;   // 6,422,528

// ---------------- workspace layout (float offsets, all 16B aligned) ----------------
constexpr size_t O_H     = 0;           // h fp32 (NTOK x 196)
constexpr size_t O_H16   = 3211264;     // h f16 (NTOK x 224)
constexpr size_t O_XI_F  = 5046272;     // xiT f32 -> dlT f32 -> fo f32
constexpr size_t O_XI_B  = 11468800;
constexpr size_t O_Z_F   = 17891328;    // zT f16; later ysT16 tok-major f16
constexpr size_t O_Z_B   = 24313856;
constexpr size_t O_XC_F  = 30736384;    // xcT f32; later head partials
constexpr size_t O_XC_B  = 37158912;
constexpr size_t O_DTR_F = 43581440;    // dt f32 (NTOK x 13)
constexpr size_t O_DTR_B = 43794432;
constexpr size_t O_BC_F  = 44007424;    // BC state-major [16][32][1024] f32
constexpr size_t O_BC_B  = 44531712;
constexpr size_t O_YS_F  = 45056000;    // early Xp f16; later y16 chain-major
constexpr size_t O_YS_B  = 48267264;    // early tok_raw f32; later y16
constexpr size_t O_PW16  = 51478528;    // patch_w f16 192x192 (36864 f16)
constexpr size_t O_FIN16 = 51496960;    // f_in_w f16 784x224
constexpr size_t O_BIN16 = 51584768;
constexpr size_t O_FOUT16= 51672576;    // f_out_w f16 196x416
constexpr size_t O_BOUT16= 51713344;    // end 51,754,112 (~198 MiB)

typedef _Float16 half8 __attribute__((ext_vector_type(8)));
typedef _Float16 half4v __attribute__((ext_vector_type(4)));
typedef float f32x4v __attribute__((ext_vector_type(4)));

// ---------------- helpers ----------------
__device__ __forceinline__ float siluf(float x) {
    return x / (1.f + __expf(-x));
}

__device__ __forceinline__ float blk_sum(float v, float* red) {
    #pragma unroll
    for (int o = 32; o > 0; o >>= 1) v += __shfl_down(v, o);
    int w = threadIdx.x >> 6;
    __syncthreads();
    if ((threadIdx.x & 63) == 0) red[w] = v;
    __syncthreads();
    return red[0] + red[1] + red[2] + red[3];
}

// ---------------- cvt all 5 weight tensors in one launch ----------------
__global__ __launch_bounds__(256) void cvt_all(const float* __restrict__ pw,
                                               const float* __restrict__ fin,
                                               const float* __restrict__ bin,
                                               const float* __restrict__ fout,
                                               const float* __restrict__ bout,
                                               _Float16* __restrict__ dst) {
    int i = blockIdx.x * 256 + threadIdx.x;       // < 551168
    const float* src; int K, Kp, off;
    if (i < 36864)       { src = pw;   K = 192; Kp = 192; off = i; }
    else if (i < 212480) { src = fin;  K = 196; Kp = 224; off = i - 36864; }
    else if (i < 388096) { src = bin;  K = 196; Kp = 224; off = i - 212480; }
    else if (i < 469632) { src = fout; K = 392; Kp = 416; off = i - 388096; }
    else                 { src = bout; K = 392; Kp = 416; off = i - 469632; }
    int n = off / Kp, k = off - n * Kp;
    dst[i] = (_Float16)(k < K ? src[(size_t)n * K + k] : 0.f);
}

// ---------------- K0: gather patches into (NTOK, 192) f16 ----------------
__global__ __launch_bounds__(256) void gather_patch(const float* __restrict__ x,
                                                    _Float16* __restrict__ Xp) {
    int i = blockIdx.x * 256 + threadIdx.x;
    int tok = i / 192, r = i - tok * 192;
    int c = r >> 6, pq = r & 63, p = pq >> 3, q = pq & 7;
    int b = tok >> 10, l = tok & 1023, hh = l >> 5, wv = l & 31;
    Xp[i] = (_Float16)x[(((size_t)(b * 3 + c) * 256 + hh * 8 + p) << 8) + wv * 8 + q];
}

// ---------------- shared MFMA GEMM core ----------------
// block 256 = 4 waves; tile 128(m) x 64(n); A tok-major f16; optional per-1024 flip.
// MODE 0: C fp32 tok-major (+bias); MODE 1: C fp32 chain-major; MODE 2: C f16 chain-major
template <int MODE>
__device__ __forceinline__ void mfma_core(const _Float16* __restrict__ A,
                                          const _Float16* __restrict__ W,
                                          const float* __restrict__ bias,
                                          void* __restrict__ Cv_,
                                          int N, int Kpad, int ldc,
                                          int flip, int m_blk, int n_blk) {
    const int tid = threadIdx.x;
    const int wv = tid >> 6, lane = tid & 63;
    const int col = lane & 15, quad = lane >> 4;
    const int m_base = m_blk * 128 + wv * 32;
    const int n_base = n_blk * 64;

    int r0 = m_base + col, r1 = m_base + 16 + col;
    if (flip) {
        r0 = (r0 & ~1023) + (1023 - (r0 & 1023));
        r1 = (r1 & ~1023) + (1023 - (r1 & 1023));
    }
    const _Float16* a0p = A + (size_t)r0 * Kpad + quad * 8;
    const _Float16* a1p = A + (size_t)r1 * Kpad + quad * 8;

    const _Float16* bp[4];
    bool bok[4];
    #pragma unroll
    for (int j = 0; j < 4; ++j) {
        int n = n_base + j * 16 + col;
        bok[j] = (n < N);
        bp[j] = W + (size_t)(bok[j] ? n : 0) * Kpad + quad * 8;
    }

    f32x4v acc[2][4];
    #pragma unroll
    for (int i = 0; i < 2; ++i)
        #pragma unroll
        for (int j = 0; j < 4; ++j)
            #pragma unroll
            for (int r = 0; r < 4; ++r) acc[i][j][r] = 0.f;

    half8 bzero;
    #pragma unroll
    for (int q = 0; q < 8; ++q) bzero[q] = (_Float16)0.f;

    for (int k0 = 0; k0 < Kpad; k0 += 32) {
        half8 a0 = *(const half8*)(a0p + k0);
        half8 a1 = *(const half8*)(a1p + k0);
        #pragma unroll
        for (int j = 0; j < 4; ++j) {
            half8 bv = bzero;
            if (bok[j]) bv = *(const half8*)(bp[j] + k0);
            acc[0][j] = __builtin_amdgcn_mfma_f32_16x16x32_f16(a0, bv, acc[0][j], 0, 0, 0);
            acc[1][j] = __builtin_amdgcn_mfma_f32_16x16x32_f16(a1, bv, acc[1][j], 0, 0, 0);
        }
    }

    if (MODE == 0) {
        float* C = (float*)Cv_;
        #pragma unroll
        for (int i = 0; i < 2; ++i) {
            int mrow = m_base + i * 16 + quad * 4;
            #pragma unroll
            for (int j = 0; j < 4; ++j) {
                int n = n_base + j * 16 + col;
                if (n < N) {
                    float bv = bias ? bias[n] : 0.f;
                    #pragma unroll
                    for (int r = 0; r < 4; ++r)
                        C[(size_t)(mrow + r) * ldc + n] = acc[i][j][r] + bv;
                }
            }
        }
    } else {
        const int bb = m_base >> 10;
        const int t0 = m_base & 1023;
        #pragma unroll
        for (int i = 0; i < 2; ++i) {
            int tt = t0 + i * 16 + quad * 4;
            #pragma unroll
            for (int j = 0; j < 4; ++j) {
                int n = n_base + j * 16 + col;
                if (n < N) {
                    if (MODE == 1) {
                        float4 v = {acc[i][j][0], acc[i][j][1], acc[i][j][2], acc[i][j][3]};
                        *(float4*)((float*)Cv_ + (((size_t)(bb * N + n)) << 10) + tt) = v;
                    } else {
                        half4v v;
                        #pragma unroll
                        for (int r = 0; r < 4; ++r) v[r] = (_Float16)acc[i][j][r];
                        *(half4v*)((_Float16*)Cv_ + (((size_t)(bb * N + n)) << 10) + tt) = v;
                    }
                }
            }
        }
    }
}

// patch embed GEMM (tok-major, bias)
__global__ __launch_bounds__(256) void mfma_patch(const _Float16* __restrict__ A,
                                                  const _Float16* __restrict__ W,
                                                  const float* __restrict__ bias,
                                                  float* __restrict__ C) {
    mfma_core<0>(A, W, bias, C, 192, KP_PW, 192, 0, blockIdx.x, blockIdx.y);
}

// merged xz projections: z = {f_xi, f_z(f16), b_xi, b_z(f16)}
__global__ __launch_bounds__(256) void mfma_xz(const _Float16* __restrict__ A,
                                               const _Float16* __restrict__ Wf,
                                               const _Float16* __restrict__ Wb,
                                               float* __restrict__ C0, _Float16* __restrict__ C1,
                                               float* __restrict__ C2, _Float16* __restrict__ C3) {
    const int zi = blockIdx.z;
    const _Float16* W = (zi < 2 ? Wf : Wb) + (size_t)(zi & 1) * DI * KP_XZ;
    const int flip = zi >> 1;
    if (zi == 0)      mfma_core<1>(A, W, nullptr, C0, DI, KP_XZ, 0, flip, blockIdx.x, blockIdx.y);
    else if (zi == 1) mfma_core<2>(A, W, nullptr, C1, DI, KP_XZ, 0, flip, blockIdx.x, blockIdx.y);
    else if (zi == 2) mfma_core<1>(A, W, nullptr, C2, DI, KP_XZ, 0, flip, blockIdx.x, blockIdx.y);
    else              mfma_core<2>(A, W, nullptr, C3, DI, KP_XZ, 0, flip, blockIdx.x, blockIdx.y);
}

// merged out-projections: z = {fwd, bwd}
__global__ __launch_bounds__(256) void mfma_op(const _Float16* __restrict__ Af,
                                               const _Float16* __restrict__ Ab,
                                               const _Float16* __restrict__ Wf,
                                               const _Float16* __restrict__ Wb,
                                               float* __restrict__ Cf, float* __restrict__ Cb) {
    const int zi = blockIdx.z;
    mfma_core<0>(zi ? Ab : Af, zi ? Wb : Wf, nullptr, zi ? Cb : Cf,
                 DM, KP_OP, DM, 0, blockIdx.x, blockIdx.y);
}

// ---------------- K1b: LN + SiLU + pos -> h fp32 + h f16; one wave per token ----------------
__global__ __launch_bounds__(256) void ln_silu_pos(const float* __restrict__ tok,
                                                   const float* __restrict__ g,
                                                   const float* __restrict__ bb,
                                                   float* __restrict__ h,
                                                   _Float16* __restrict__ h16) {
    const int w = threadIdx.x >> 6, lane = threadIdx.x & 63;
    const int t = blockIdx.x * 4 + w;
    const float* tp = tok + (size_t)t * E_;
    float v[3];
    float s1 = 0.f, s2 = 0.f;
    #pragma unroll
    for (int i = 0; i < 3; ++i) {
        v[i] = tp[lane + i * 64];
        s1 += v[i];
        s2 = fmaf(v[i], v[i], s2);
    }
    #pragma unroll
    for (int o = 32; o > 0; o >>= 1) {
        s1 += __shfl_xor(s1, o);
        s2 += __shfl_xor(s2, o);
    }
    float mean = s1 * (1.f / E_);
    float var = s2 * (1.f / E_) - mean * mean;
    float inv = rsqrtf(var + 1e-5f);
    float* hp = h + (size_t)t * DM;
    _Float16* hq = h16 + (size_t)t * KP_XZ;
    #pragma unroll
    for (int i = 0; i < 3; ++i) {
        int e = lane + i * 64;
        float o = siluf((v[i] - mean) * inv * g[e] + bb[e]);
        hp[e] = o;
        hq[e] = (_Float16)o;
    }
    const int l = t & 1023;
    const float scale = 0.19634954084936207f;  // 2*pi/32
    if (lane < 4) {
        float pv = (lane == 0) ? sinf(l * scale)
                 : (lane == 1) ? cosf(l * scale)
                 : (lane == 2) ? sinf((float)(l >> 5) * scale)
                 :               cosf((float)(l >> 5) * scale);
        hp[E_ + lane] = pv;
        hq[E_ + lane] = (_Float16)pv;
    } else if (lane < 32) {
        hq[192 + lane] = (_Float16)0.f;   // pad 196..223
    }
}

// ---------------- K3: depthwise causal conv(4)+SiLU chain-major ----------------
__global__ __launch_bounds__(256) void conv_silu_T(
        const float* __restrict__ xiT_f, const float* __restrict__ xiT_b,
        float* __restrict__ xcT_f, float* __restrict__ xcT_b,
        const float* __restrict__ fw, const float* __restrict__ fb,
        const float* __restrict__ bw, const float* __restrict__ bb2) {
    int i = blockIdx.x * 256 + threadIdx.x;        // < 2*CH*256
    int rall = i >> 8;
    int dir = rall >= CH;
    int r = rall - (dir ? CH : 0);
    int d = r % DI;
    int t0 = (i & 255) << 2;
    const float* xi = (dir ? xiT_b : xiT_f) + ((size_t)r << 10) + t0;
    float cur[4], prev[4] = {0.f, 0.f, 0.f, 0.f};
    *(float4*)cur = *(const float4*)xi;
    if (t0) *(float4*)prev = *(const float4*)(xi - 4);
    const float* w = (dir ? bw : fw) + d * 4;
    float bias = (dir ? bb2 : fb)[d];
    float xv[7] = {prev[1], prev[2], prev[3], cur[0], cur[1], cur[2], cur[3]};
    float o[4];
    #pragma unroll
    for (int tt = 0; tt < 4; ++tt) {
        float a = bias;
        #pragma unroll
        for (int k = 0; k < 4; ++k) a = fmaf(xv[tt + k], w[k], a);
        o[tt] = siluf(a);
    }
    *(float4*)((dir ? xcT_b : xcT_f) + ((size_t)r << 10) + t0) = *(float4*)o;
}

// ---------------- K2b: x_dbl GEMM (fp32), both dirs; dt tok-major, BC state-major ----------------
__global__ __launch_bounds__(256) void gemm_xdbl(const float* __restrict__ Af,
                                                 const float* __restrict__ Ab,
                                                 const float* __restrict__ Wf,
                                                 const float* __restrict__ Wb,
                                                 float* __restrict__ dtrf,
                                                 float* __restrict__ dtrb,
                                                 float* __restrict__ bcf,
                                                 float* __restrict__ bcb) {
    const int yi = blockIdx.y;
    const float* A = yi ? Ab : Af;
    const float* W = yi ? Wb : Wf;
    float* dtr = yi ? dtrb : dtrf;
    float* bc = yi ? bcb : bcf;
    __shared__ __align__(16) float As[16][68];
    __shared__ __align__(16) float Ws[16][68];
    __shared__ __align__(16) float Ls[32][68];
    const int m0 = blockIdx.x * 64;
    const int t = threadIdx.x;
    const int tx = t & 15, ty = t >> 4;
    float acc[4][4] = {};
    const int arow_l = t >> 2;
    const int kq = (t & 3) * 4;
    const int bb_ = m0 >> 10, tt0 = m0 & 1023;
    for (int kt = 0; kt < 25; ++kt) {              // K=392: 24*16+8
        const int k0 = kt << 4;
        {
            int kr = t >> 4, tc = t & 15;
            int kk = k0 + kr;
            float4 v = {0.f, 0.f, 0.f, 0.f};
            if (kk < DI)
                v = *(const float4*)(A + (((size_t)bb_ * DI + kk) << 10) + tt0 + tc * 4);
            *(float4*)&As[kr][tc * 4] = v;
        }
        {
            bool okn = arow_l < XDW;
            const float* wp = W + (size_t)arow_l * DI;
            #pragma unroll
            for (int jj = 0; jj < 4; ++jj) {
                int kk = k0 + kq + jj;
                Ws[kq + jj][arow_l] = (okn && kk < DI) ? wp[kk] : 0.f;
            }
        }
        __syncthreads();
        #pragma unroll
        for (int k = 0; k < 16; ++k) {
            float av[4], wv[4];
            *(float4*)av = *(const float4*)&As[k][ty * 4];
            *(float4*)wv = *(const float4*)&Ws[k][tx * 4];
            #pragma unroll
            for (int i = 0; i < 4; ++i)
                #pragma unroll
                for (int j = 0; j < 4; ++j)
                    acc[i][j] = fmaf(av[i], wv[j], acc[i][j]);
        }
        __syncthreads();
    }
    // dt: direct store; BC: stash in LDS for transposed store
    #pragma unroll
    for (int i = 0; i < 4; ++i) {
        int m = m0 + ty * 4 + i;
        #pragma unroll
        for (int j = 0; j < 4; ++j) {
            int n = tx * 4 + j;
            float v = acc[i][j];
            if (n < DTR) dtr[(size_t)m * DTR + n] = v;
            else if (n < XDW) Ls[n - DTR][ty * 4 + i] = v;
        }
    }
    __syncthreads();
    {
        int nn = t >> 3;              // 0..31
        int tq = (t & 7) * 8;         // 0..56
        float4 v0 = *(const float4*)&Ls[nn][tq];
        float4 v1 = *(const float4*)&Ls[nn][tq + 4];
        float* dst = bc + (((size_t)(bb_ * 32 + nn)) << 10) + tt0 + tq;
        *(float4*)dst = v0;
        *(float4*)(dst + 4) = v1;
    }
}

// ---------------- K4: delta = softplus(dt @ dt_w^T + dt_b) -> chain-major ----------------
__global__ __launch_bounds__(256) void delta_kernel(
        const float* __restrict__ dtr_f, const float* __restrict__ dtr_b,
        float* __restrict__ dlT_f, float* __restrict__ dlT_b,
        const float* __restrict__ f_dt_w, const float* __restrict__ f_dt_b,
        const float* __restrict__ b_dt_w, const float* __restrict__ b_dt_b) {
    int i = blockIdx.x * 256 + threadIdx.x;       // < 2*DI_SZ
    int dir = i >= (int)DI_SZ;
    int j = dir ? i - (int)DI_SZ : i;             // r*1024 + t
    int r = j >> 10, t = j & 1023;
    int b = r / DI, d = r - (r / DI) * DI;
    size_t tok = ((size_t)b << 10) + t;
    const float* xd = (dir ? dtr_b : dtr_f) + tok * DTR;
    const float* w = (dir ? b_dt_w : f_dt_w) + d * DTR;
    float acc = (dir ? b_dt_b : f_dt_b)[d];
    #pragma unroll
    for (int q = 0; q < DTR; ++q) acc = fmaf(xd[q], w[q], acc);
    float sp = fmaxf(acc, 0.f) + log1pf(__expf(-fabsf(acc)));
    (dir ? dlT_b : dlT_f)[j] = sp;
}

// ---------------- K5: 2-pass chunked scan, 16 lanes/chain x 1 state, fused gate ----------------
// block 256 = 2 chains x 8 chunks x 16 states; grid = CH (covers 2*CH chains).
// Phase C chunk == one 128-t store window: owner lane n packs t-window n*8..n*8+8.
__global__ __launch_bounds__(256) void scan_kernel(
        const float* __restrict__ dlT_f, const float* __restrict__ dlT_b,
        const float* __restrict__ xcT_f, const float* __restrict__ xcT_b,
        const float* __restrict__ bct_f, const float* __restrict__ bct_b,
        const _Float16* __restrict__ zT_f, const _Float16* __restrict__ zT_b,
        _Float16* __restrict__ y16_f,    _Float16* __restrict__ y16_b,
        const float* __restrict__ fA, const float* __restrict__ bA,
        const float* __restrict__ fD, const float* __restrict__ bD) {
    __shared__ float sP[2][8][16];
    __shared__ float sH[2][8][16];
    __shared__ float sI[2][8][16];
    const int tid = threadIdx.x;
    const int cl = tid >> 7;
    const int c  = (tid >> 4) & 7;
    const int n  = tid & 15;
    const int chain = blockIdx.x * 2 + cl;
    const int dir = chain >= CH;
    const int r = chain - (dir ? CH : 0);
    const int b = r / DI, d = r - (r / DI) * DI;

    const float* dl = (dir ? dlT_b : dlT_f) + ((size_t)r << 10);
    const float* uT = (dir ? xcT_b : xcT_f) + ((size_t)r << 10);
    const _Float16* zT = (dir ? zT_b : zT_f) + ((size_t)r << 10);
    const float* Bp = (dir ? bct_b : bct_f) + (((size_t)(b * 32 + n)) << 10);
    const float* Cp = Bp + (16 << 10);
    _Float16* y16 = (dir ? y16_b : y16_f) + ((size_t)r << 10);
    // fold 1/ln2 into A so dA = exp2f(dv*Av2) is a bare v_exp_f32
    const float Av2 = -__expf((dir ? bA : fA)[d * DS + n]) * 1.4426950408889634f;
    const float Dd = (dir ? bD : fD)[d];
    const int t0 = c << 7;

    // ---- phase A: local scan, h0 = 0 ----
    if (c < 7) {
        float h = 0.f, S = 0.f;
        for (int g = 0; g < 32; ++g) {
            const int tg = t0 + g * 4;
            float4 d4 = *(const float4*)(dl + tg);
            float4 u4 = *(const float4*)(uT + tg);
            float4 B4 = *(const float4*)(Bp + tg);
            float dv[4] = {d4.x, d4.y, d4.z, d4.w};
            float uv[4] = {u4.x, u4.y, u4.z, u4.w};
            float Bv[4] = {B4.x, B4.y, B4.z, B4.w};
            #pragma unroll
            for (int tt = 0; tt < 4; ++tt) {
                float dA = exp2f(dv[tt] * Av2);
                h = fmaf(dA, h, dv[tt] * uv[tt] * Bv[tt]);
                S += dv[tt];
            }
        }
        sP[cl][c][n] = exp2f(S * Av2);
        sH[cl][c][n] = h;
    }
    __syncthreads();

    // ---- phase B: serial combine ----
    if (c == 0) {
        float hi = 0.f;
        #pragma unroll
        for (int cc = 0; cc < 8; ++cc) {
            sI[cl][cc][n] = hi;
            if (cc < 7) hi = sH[cl][cc][n] + sP[cl][cc][n] * hi;
        }
    }
    __syncthreads();

    // ---- phase C: rescan with h_init, reduce over n, gate, coalesced store ----
    {
        float h = sI[cl][c][n];
        _Float16 ybuf[8] __attribute__((aligned(16)));
        half8 zb = *(const half8*)(zT + t0 + n * 8);   // owner lane's z window
        for (int g = 0; g < 32; ++g) {
            const int tg = t0 + g * 4;
            float4 d4 = *(const float4*)(dl + tg);
            float4 u4 = *(const float4*)(uT + tg);
            float4 B4 = *(const float4*)(Bp + tg);
            float4 C4 = *(const float4*)(Cp + tg);
            float dv[4] = {d4.x, d4.y, d4.z, d4.w};
            float uv[4] = {u4.x, u4.y, u4.z, u4.w};
            float Bv[4] = {B4.x, B4.y, B4.z, B4.w};
            float Cv[4] = {C4.x, C4.y, C4.z, C4.w};
            float pq[4];
            #pragma unroll
            for (int tt = 0; tt < 4; ++tt) {
                float dA = exp2f(dv[tt] * Av2);
                h = fmaf(dA, h, dv[tt] * uv[tt] * Bv[tt]);
                float p = h * Cv[tt];
                p += __shfl_xor(p, 1);
                p += __shfl_xor(p, 2);
                p += __shfl_xor(p, 4);
                p += __shfl_xor(p, 8);
                pq[tt] = p;
            }
            if (((g >> 1) & 15) == n) {
                const int base = (g & 1) * 4;
                #pragma unroll
                for (int tt = 0; tt < 4; ++tt)
                    ybuf[base + tt] =
                        (_Float16)((pq[tt] + Dd * uv[tt]) * siluf((float)zb[base + tt]));
            }
        }
        *(half8*)(y16 + t0 + n * 8) = *(half8*)ybuf;
    }
}

// ---------------- K5b: transpose y16 chain-major -> tok-major f16 padded 416 ----------------
__global__ __launch_bounds__(256) void transp_y(
        const _Float16* __restrict__ yf, const _Float16* __restrict__ yb,
        _Float16* __restrict__ of, _Float16* __restrict__ ob) {
    __shared__ _Float16 tile[64][72];
    const int dblk = blockIdx.z % 7, dir = blockIdx.z / 7;
    const int b = blockIdx.y, tb = blockIdx.x;
    const _Float16* y = dir ? yb : yf;
    _Float16* o = dir ? ob : of;
    const int d0 = dblk * 64, t0 = tb * 64;
    const int dl = threadIdx.x >> 2, ts = (threadIdx.x & 3) * 16;
    const int d = d0 + dl;
    if (d < DI) {
        const _Float16* src = y + (((size_t)(b * DI + d)) << 10) + t0 + ts;
        *(half8*)&tile[dl][ts] = *(const half8*)src;
        *(half8*)&tile[dl][ts + 8] = *(const half8*)(src + 8);
    } else {
        #pragma unroll
        for (int q = 0; q < 16; ++q) tile[dl][ts + q] = (_Float16)0.f;
    }
    __syncthreads();
    const int tl = threadIdx.x >> 2, ds = (threadIdx.x & 3) * 16;
    if (d0 + ds < KP_OP) {
        _Float16 v[16] __attribute__((aligned(16)));
        #pragma unroll
        for (int q = 0; q < 16; ++q) v[q] = tile[ds + q][tl];
        _Float16* dst = o + ((size_t)((b << 10) + t0 + tl)) * KP_OP + d0 + ds;
        *(half8*)dst = *(half8*)&v[0];
        *(half8*)(dst + 8) = *(half8*)&v[8];
    }
}

// ---------------- K8a: head partials — one wave per token, no atomics ----------------
__global__ __launch_bounds__(256) void final_head(
        const float* __restrict__ fo, const float* __restrict__ bo,
        const float* __restrict__ h, const float* __restrict__ g,
        const float* __restrict__ bb, const float* __restrict__ cls_w,
        float* __restrict__ partial) {
    const int w = threadIdx.x >> 6, lane = threadIdx.x & 63;
    const int t = blockIdx.x * 4 + w;
    const int b = t >> 10, l = t & 1023;
    const float* fp = fo + (size_t)t * DM;
    const float* bp = bo + ((size_t)(b << 10) + (1023 - l)) * DM;
    const float* hp = h + (size_t)t * DM;
    float v[4];
    float s1 = 0.f, s2 = 0.f;
    #pragma unroll
    for (int i = 0; i < 4; ++i) {
        int e = lane + i * 64;
        bool ok = (i < 3) || (lane < 4);
        float vv = ok ? 0.5f * (fp[e] + bp[e]) : 0.f;
        v[i] = vv;
        s1 += vv;
        s2 = fmaf(vv, vv, s2);
    }
    #pragma unroll
    for (int o = 32; o > 0; o >>= 1) {
        s1 += __shfl_xor(s1, o);
        s2 += __shfl_xor(s2, o);
    }
    float mean = s1 * (1.f / DM);
    float var = s2 * (1.f / DM) - mean * mean;
    float inv = rsqrtf(var + 1e-5f);
    float c = 0.f;
    #pragma unroll
    for (int i = 0; i < 4; ++i) {
        int e = lane + i * 64;
        bool ok = (i < 3) || (lane < 4);
        if (ok) {
            float o2 = (v[i] - mean) * inv * g[e] + bb[e];
            o2 = siluf(o2) + hp[e];
            c = fmaf(o2, cls_w[e], c);
        }
    }
    #pragma unroll
    for (int o = 32; o > 0; o >>= 1) c += __shfl_xor(c, o);
    if (lane == 0) partial[t] = c;
}

// ---------------- K8b: reduce 1024 partials per batch -> out ----------------
__global__ __launch_bounds__(256) void head_reduce(const float* __restrict__ partial,
                                                   const float* __restrict__ cls_b,
                                                   float* __restrict__ out) {
    __shared__ float red[4];
    const int b = blockIdx.x;
    const float* p = partial + ((size_t)b << 10);
    float s = 0.f;
    for (int i = threadIdx.x; i < 1024; i += 256) s += p[i];
    s = blk_sum(s, red);
    if (threadIdx.x == 0) out[b] = s * (1.f / 1024.f) + cls_b[0];
}

// ---------------- launch ----------------
extern "C" void kernel_launch(void* const* d_in, const int* in_sizes, int n_in,
                              void* d_out, int out_size, void* d_ws, size_t ws_size,
                              hipStream_t stream) {
    const float* x        = (const float*)d_in[0];
    const float* patch_w  = (const float*)d_in[1];
    const float* patch_b  = (const float*)d_in[2];
    const float* pe_g     = (const float*)d_in[3];
    const float* pe_b     = (const float*)d_in[4];
    const float* blk_g    = (const float*)d_in[5];
    const float* blk_b    = (const float*)d_in[6];
    const float* cls_w    = (const float*)d_in[7];
    const float* cls_b    = (const float*)d_in[8];
    const float* f_in_w   = (const float*)d_in[9];
    const float* f_conv_w = (const float*)d_in[10];
    const float* f_conv_b = (const float*)d_in[11];
    const float* f_xp_w   = (const float*)d_in[12];
    const float* f_dt_w   = (const float*)d_in[13];
    const float* f_dt_b   = (const float*)d_in[14];
    const float* f_A_log  = (const float*)d_in[15];
    const float* f_D      = (const float*)d_in[16];
    const float* f_out_w  = (const float*)d_in[17];
    const float* b_in_w   = (const float*)d_in[18];
    const float* b_conv_w = (const float*)d_in[19];
    const float* b_conv_b = (const float*)d_in[20];
    const float* b_xp_w   = (const float*)d_in[21];
    const float* b_dt_w   = (const float*)d_in[22];
    const float* b_dt_b   = (const float*)d_in[23];
    const float* b_A_log  = (const float*)d_in[24];
    const float* b_D      = (const float*)d_in[25];
    const float* b_out_w  = (const float*)d_in[26];

    float* ws = (float*)d_ws;
    float* out = (float*)d_out;

    float* Hb        = ws + O_H;
    _Float16* H16    = (_Float16*)(ws + O_H16);
    float* XIf       = ws + O_XI_F;
    float* XIb       = ws + O_XI_B;
    _Float16* ZT16f  = (_Float16*)(ws + O_Z_F);   // zT f16 chain-major
    _Float16* ZT16b  = (_Float16*)(ws + O_Z_B);
    _Float16* YsTf16 = (_Float16*)(ws + O_Z_F);   // after transp: tok-major ys f16
    _Float16* YsTb16 = (_Float16*)(ws + O_Z_B);
    float* XCf       = ws + O_XC_F;               // xcT_f; later head partials
    float* XCb       = ws + O_XC_B;
    float* DTRf      = ws + O_DTR_F;
    float* DTRb      = ws + O_DTR_B;
    float* BCf       = ws + O_BC_F;               // state-major [16][32][1024]
    float* BCb       = ws + O_BC_B;
    _Float16* Xp16   = (_Float16*)(ws + O_YS_F);  // early
    float* TokRaw    = ws + O_YS_B;               // early
    _Float16* Y16f   = (_Float16*)(ws + O_YS_F);  // after scan
    _Float16* Y16b   = (_Float16*)(ws + O_YS_B);
    _Float16* PW16   = (_Float16*)(ws + O_PW16);
    _Float16* FIN16  = (_Float16*)(ws + O_FIN16);
    _Float16* BIN16  = (_Float16*)(ws + O_BIN16);
    _Float16* FOUT16 = (_Float16*)(ws + O_FOUT16);
    _Float16* BOUT16 = (_Float16*)(ws + O_BOUT16);

    // weight conversions (single launch, dst regions contiguous from PW16)
    cvt_all<<<2153, 256, 0, stream>>>(patch_w, f_in_w, b_in_w, f_out_w, b_out_w, PW16);

    // patch embed
    gather_patch<<<(NTOK * 192) / 256, 256, 0, stream>>>(x, Xp16);
    mfma_patch<<<dim3(NTOK / 128, 3), 256, 0, stream>>>(Xp16, PW16, patch_b, TokRaw);
    ln_silu_pos<<<NTOK / 4, 256, 0, stream>>>(TokRaw, pe_g, pe_b, Hb, H16);

    // xz projections -> chain-major (xi fp32, z f16)
    mfma_xz<<<dim3(NTOK / 128, 7, 4), 256, 0, stream>>>(H16, FIN16, BIN16,
                                                        XIf, ZT16f, XIb, ZT16b);
    // conv + silu
    conv_silu_T<<<2 * CH, 256, 0, stream>>>(XIf, XIb, XCf, XCb,
                                            f_conv_w, f_conv_b, b_conv_w, b_conv_b);
    // x_dbl (fp32) -> dt tok-major + BC state-major (merged dirs)
    gemm_xdbl<<<dim3(NTOK / 64, 2), 256, 0, stream>>>(XCf, XCb, f_xp_w, b_xp_w,
                                                      DTRf, DTRb, BCf, BCb);
    // delta -> dlT (overwrites dead xiT)
    delta_kernel<<<(2 * (int)DI_SZ) / 256, 256, 0, stream>>>(
        DTRf, DTRb, XIf, XIb, f_dt_w, f_dt_b, b_dt_w, b_dt_b);
    // 2-pass chunked scan + fused gate -> y16 chain-major
    scan_kernel<<<CH, 256, 0, stream>>>(
        XIf, XIb, XCf, XCb, BCf, BCb, ZT16f, ZT16b, Y16f, Y16b,
        f_A_log, b_A_log, f_D, b_D);
    // transpose -> tok-major f16 (into dead Z regions)
    transp_y<<<dim3(16, 16, 14), 256, 0, stream>>>(Y16f, Y16b, YsTf16, YsTb16);
    // out projections -> fo/bo fp32 tok-major (merged dirs)
    mfma_op<<<dim3(NTOK / 128, 4, 2), 256, 0, stream>>>(YsTf16, YsTb16,
                                                        FOUT16, BOUT16, XIf, XIb);
    // head: partials (into dead XCf region) then reduce
    final_head<<<NTOK / 4, 256, 0, stream>>>(XIf, XIb, Hb, blk_g, blk_b, cls_w, XCf);
    head_reduce<<<B_, 256, 0, stream>>>(XCf, cls_b, out);
}

// Round 10
// 521.999 us; speedup vs baseline: 1.6576x; 1.6576x over previous
//
#include <hip/hip_runtime.h>
#include <cstdint>
#include <cstddef>

// ---------------- problem constants ----------------
constexpr int B_   = 16;
constexpr int L_   = 1024;
constexpr int E_   = 192;
constexpr int DM   = 196;   // D_MODEL
constexpr int DI   = 392;   // D_INNER
constexpr int DS   = 16;    // D_STATE
constexpr int DTR  = 13;    // DT_RANK
constexpr int NTOK = B_ * L_;            // 16384
constexpr int XDW  = DTR + 2 * DS;       // 45
constexpr int CH   = B_ * DI;            // 6272 chains per direction

constexpr int KP_XZ = 224;   // 196 padded to %32
constexpr int KP_OP = 416;   // 392 padded to %32
constexpr int KP_PW = 192;

constexpr size_t HW_SZ = (size_t)NTOK * DM;   // 3,211,264
constexpr size_t DI_SZ = (size_t)NTOK * DI;   // 6,422,528

// ---------------- workspace layout (float offsets, all 16B aligned) ----------------
constexpr size_t O_H     = 0;           // h fp32 (NTOK x 196)
constexpr size_t O_H16   = 3211264;     // h f16 (NTOK x 224)
constexpr size_t O_XI_F  = 5046272;     // xiT f32 -> dlT f32 -> fo f32
constexpr size_t O_XI_B  = 11468800;
constexpr size_t O_Z_F   = 17891328;    // silu(z)T f16; later ysT16 tok-major f16
constexpr size_t O_Z_B   = 24313856;
constexpr size_t O_XC_F  = 30736384;    // xcT f32; later head partials
constexpr size_t O_XC_B  = 37158912;
constexpr size_t O_DTR_F = 43581440;    // dt f32 (NTOK x 13)
constexpr size_t O_DTR_B = 43794432;
constexpr size_t O_BC_F  = 44007424;    // [B|C] packed tok-major (NTOK x 32) f32
constexpr size_t O_BC_B  = 44531712;
constexpr size_t O_YS_F  = 45056000;    // early Xp f16; later y16 chain-major
constexpr size_t O_YS_B  = 48267264;    // early tok_raw f32; later y16
constexpr size_t O_PW16  = 51478528;    // patch_w f16 192x192 (36864 f16)
constexpr size_t O_FIN16 = 51496960;    // f_in_w f16 784x224
constexpr size_t O_BIN16 = 51584768;
constexpr size_t O_FOUT16= 51672576;    // f_out_w f16 196x416
constexpr size_t O_BOUT16= 51713344;    // end 51,754,112 (~198 MiB)

typedef _Float16 half8 __attribute__((ext_vector_type(8)));
typedef _Float16 half4v __attribute__((ext_vector_type(4)));
typedef float f32x4v __attribute__((ext_vector_type(4)));

// ---------------- helpers ----------------
__device__ __forceinline__ float siluf(float x) {
    return x / (1.f + __expf(-x));
}

__device__ __forceinline__ float blk_sum(float v, float* red) {
    #pragma unroll
    for (int o = 32; o > 0; o >>= 1) v += __shfl_down(v, o);
    int w = threadIdx.x >> 6;
    __syncthreads();
    if ((threadIdx.x & 63) == 0) red[w] = v;
    __syncthreads();
    return red[0] + red[1] + red[2] + red[3];
}

// ---------------- cvt all 5 weight tensors in one launch ----------------
__global__ __launch_bounds__(256) void cvt_all(const float* __restrict__ pw,
                                               const float* __restrict__ fin,
                                               const float* __restrict__ bin,
                                               const float* __restrict__ fout,
                                               const float* __restrict__ bout,
                                               _Float16* __restrict__ dst) {
    int i = blockIdx.x * 256 + threadIdx.x;       // < 551168
    const float* src; int K, Kp, off;
    if (i < 36864)       { src = pw;   K = 192; Kp = 192; off = i; }
    else if (i < 212480) { src = fin;  K = 196; Kp = 224; off = i - 36864; }
    else if (i < 388096) { src = bin;  K = 196; Kp = 224; off = i - 212480; }
    else if (i < 469632) { src = fout; K = 392; Kp = 416; off = i - 388096; }
    else                 { src = bout; K = 392; Kp = 416; off = i - 469632; }
    int n = off / Kp, k = off - n * Kp;
    dst[i] = (_Float16)(k < K ? src[(size_t)n * K + k] : 0.f);
}

// ---------------- K0: gather patches into (NTOK, 192) f16 ----------------
__global__ __launch_bounds__(256) void gather_patch(const float* __restrict__ x,
                                                    _Float16* __restrict__ Xp) {
    int i = blockIdx.x * 256 + threadIdx.x;
    int tok = i / 192, r = i - tok * 192;
    int c = r >> 6, pq = r & 63, p = pq >> 3, q = pq & 7;
    int b = tok >> 10, l = tok & 1023, hh = l >> 5, wv = l & 31;
    Xp[i] = (_Float16)x[(((size_t)(b * 3 + c) * 256 + hh * 8 + p) << 8) + wv * 8 + q];
}

// ---------------- shared MFMA GEMM core ----------------
// block 256 = 4 waves; tile 128(m) x 64(n); A tok-major f16; optional per-1024 flip.
// MODE 0: C fp32 tok-major (+bias); MODE 1: C fp32 chain-major;
// MODE 3: C f16 chain-major with silu applied (for z gate path)
template <int MODE>
__device__ __forceinline__ void mfma_core(const _Float16* __restrict__ A,
                                          const _Float16* __restrict__ W,
                                          const float* __restrict__ bias,
                                          void* __restrict__ Cv_,
                                          int N, int Kpad, int ldc,
                                          int flip, int m_blk, int n_blk) {
    const int tid = threadIdx.x;
    const int wv = tid >> 6, lane = tid & 63;
    const int col = lane & 15, quad = lane >> 4;
    const int m_base = m_blk * 128 + wv * 32;
    const int n_base = n_blk * 64;

    int r0 = m_base + col, r1 = m_base + 16 + col;
    if (flip) {
        r0 = (r0 & ~1023) + (1023 - (r0 & 1023));
        r1 = (r1 & ~1023) + (1023 - (r1 & 1023));
    }
    const _Float16* a0p = A + (size_t)r0 * Kpad + quad * 8;
    const _Float16* a1p = A + (size_t)r1 * Kpad + quad * 8;

    const _Float16* bp[4];
    bool bok[4];
    #pragma unroll
    for (int j = 0; j < 4; ++j) {
        int n = n_base + j * 16 + col;
        bok[j] = (n < N);
        bp[j] = W + (size_t)(bok[j] ? n : 0) * Kpad + quad * 8;
    }

    f32x4v acc[2][4];
    #pragma unroll
    for (int i = 0; i < 2; ++i)
        #pragma unroll
        for (int j = 0; j < 4; ++j)
            #pragma unroll
            for (int r = 0; r < 4; ++r) acc[i][j][r] = 0.f;

    half8 bzero;
    #pragma unroll
    for (int q = 0; q < 8; ++q) bzero[q] = (_Float16)0.f;

    for (int k0 = 0; k0 < Kpad; k0 += 32) {
        half8 a0 = *(const half8*)(a0p + k0);
        half8 a1 = *(const half8*)(a1p + k0);
        #pragma unroll
        for (int j = 0; j < 4; ++j) {
            half8 bv = bzero;
            if (bok[j]) bv = *(const half8*)(bp[j] + k0);
            acc[0][j] = __builtin_amdgcn_mfma_f32_16x16x32_f16(a0, bv, acc[0][j], 0, 0, 0);
            acc[1][j] = __builtin_amdgcn_mfma_f32_16x16x32_f16(a1, bv, acc[1][j], 0, 0, 0);
        }
    }

    if (MODE == 0) {
        float* C = (float*)Cv_;
        #pragma unroll
        for (int i = 0; i < 2; ++i) {
            int mrow = m_base + i * 16 + quad * 4;
            #pragma unroll
            for (int j = 0; j < 4; ++j) {
                int n = n_base + j * 16 + col;
                if (n < N) {
                    float bv = bias ? bias[n] : 0.f;
                    #pragma unroll
                    for (int r = 0; r < 4; ++r)
                        C[(size_t)(mrow + r) * ldc + n] = acc[i][j][r] + bv;
                }
            }
        }
    } else {
        const int bb = m_base >> 10;
        const int t0 = m_base & 1023;
        #pragma unroll
        for (int i = 0; i < 2; ++i) {
            int tt = t0 + i * 16 + quad * 4;
            #pragma unroll
            for (int j = 0; j < 4; ++j) {
                int n = n_base + j * 16 + col;
                if (n < N) {
                    if (MODE == 1) {
                        float4 v = {acc[i][j][0], acc[i][j][1], acc[i][j][2], acc[i][j][3]};
                        *(float4*)((float*)Cv_ + (((size_t)(bb * N + n)) << 10) + tt) = v;
                    } else {
                        half4v v;
                        #pragma unroll
                        for (int r = 0; r < 4; ++r) {
                            float xx = acc[i][j][r];
                            v[r] = (_Float16)(xx / (1.f + __expf(-xx)));   // silu
                        }
                        *(half4v*)((_Float16*)Cv_ + (((size_t)(bb * N + n)) << 10) + tt) = v;
                    }
                }
            }
        }
    }
}

// patch embed GEMM (tok-major, bias)
__global__ __launch_bounds__(256) void mfma_patch(const _Float16* __restrict__ A,
                                                  const _Float16* __restrict__ W,
                                                  const float* __restrict__ bias,
                                                  float* __restrict__ C) {
    mfma_core<0>(A, W, bias, C, 192, KP_PW, 192, 0, blockIdx.x, blockIdx.y);
}

// merged xz projections: z = {f_xi, f_z(silu f16), b_xi, b_z(silu f16)}
__global__ __launch_bounds__(256) void mfma_xz(const _Float16* __restrict__ A,
                                               const _Float16* __restrict__ Wf,
                                               const _Float16* __restrict__ Wb,
                                               float* __restrict__ C0, _Float16* __restrict__ C1,
                                               float* __restrict__ C2, _Float16* __restrict__ C3) {
    const int zi = blockIdx.z;
    const _Float16* W = (zi < 2 ? Wf : Wb) + (size_t)(zi & 1) * DI * KP_XZ;
    const int flip = zi >> 1;
    if (zi == 0)      mfma_core<1>(A, W, nullptr, C0, DI, KP_XZ, 0, flip, blockIdx.x, blockIdx.y);
    else if (zi == 1) mfma_core<3>(A, W, nullptr, C1, DI, KP_XZ, 0, flip, blockIdx.x, blockIdx.y);
    else if (zi == 2) mfma_core<1>(A, W, nullptr, C2, DI, KP_XZ, 0, flip, blockIdx.x, blockIdx.y);
    else              mfma_core<3>(A, W, nullptr, C3, DI, KP_XZ, 0, flip, blockIdx.x, blockIdx.y);
}

// merged out-projections: z = {fwd, bwd}
__global__ __launch_bounds__(256) void mfma_op(const _Float16* __restrict__ Af,
                                               const _Float16* __restrict__ Ab,
                                               const _Float16* __restrict__ Wf,
                                               const _Float16* __restrict__ Wb,
                                               float* __restrict__ Cf, float* __restrict__ Cb) {
    const int zi = blockIdx.z;
    mfma_core<0>(zi ? Ab : Af, zi ? Wb : Wf, nullptr, zi ? Cb : Cf,
                 DM, KP_OP, DM, 0, blockIdx.x, blockIdx.y);
}

// ---------------- K1b: LN + SiLU + pos -> h fp32 + h f16; one wave per token ----------------
__global__ __launch_bounds__(256) void ln_silu_pos(const float* __restrict__ tok,
                                                   const float* __restrict__ g,
                                                   const float* __restrict__ bb,
                                                   float* __restrict__ h,
                                                   _Float16* __restrict__ h16) {
    const int w = threadIdx.x >> 6, lane = threadIdx.x & 63;
    const int t = blockIdx.x * 4 + w;
    const float* tp = tok + (size_t)t * E_;
    float v[3];
    float s1 = 0.f, s2 = 0.f;
    #pragma unroll
    for (int i = 0; i < 3; ++i) {
        v[i] = tp[lane + i * 64];
        s1 += v[i];
        s2 = fmaf(v[i], v[i], s2);
    }
    #pragma unroll
    for (int o = 32; o > 0; o >>= 1) {
        s1 += __shfl_xor(s1, o);
        s2 += __shfl_xor(s2, o);
    }
    float mean = s1 * (1.f / E_);
    float var = s2 * (1.f / E_) - mean * mean;
    float inv = rsqrtf(var + 1e-5f);
    float* hp = h + (size_t)t * DM;
    _Float16* hq = h16 + (size_t)t * KP_XZ;
    #pragma unroll
    for (int i = 0; i < 3; ++i) {
        int e = lane + i * 64;
        float o = siluf((v[i] - mean) * inv * g[e] + bb[e]);
        hp[e] = o;
        hq[e] = (_Float16)o;
    }
    const int l = t & 1023;
    const float scale = 0.19634954084936207f;  // 2*pi/32
    if (lane < 4) {
        float pv = (lane == 0) ? sinf(l * scale)
                 : (lane == 1) ? cosf(l * scale)
                 : (lane == 2) ? sinf((float)(l >> 5) * scale)
                 :               cosf((float)(l >> 5) * scale);
        hp[E_ + lane] = pv;
        hq[E_ + lane] = (_Float16)pv;
    } else if (lane < 32) {
        hq[192 + lane] = (_Float16)0.f;   // pad 196..223
    }
}

// ---------------- K3: depthwise causal conv(4)+SiLU chain-major ----------------
__global__ __launch_bounds__(256) void conv_silu_T(
        const float* __restrict__ xiT_f, const float* __restrict__ xiT_b,
        float* __restrict__ xcT_f, float* __restrict__ xcT_b,
        const float* __restrict__ fw, const float* __restrict__ fb,
        const float* __restrict__ bw, const float* __restrict__ bb2) {
    int i = blockIdx.x * 256 + threadIdx.x;        // < 2*CH*256
    int rall = i >> 8;
    int dir = rall >= CH;
    int r = rall - (dir ? CH : 0);
    int d = r % DI;
    int t0 = (i & 255) << 2;
    const float* xi = (dir ? xiT_b : xiT_f) + ((size_t)r << 10) + t0;
    float cur[4], prev[4] = {0.f, 0.f, 0.f, 0.f};
    *(float4*)cur = *(const float4*)xi;
    if (t0) *(float4*)prev = *(const float4*)(xi - 4);
    const float* w = (dir ? bw : fw) + d * 4;
    float bias = (dir ? bb2 : fb)[d];
    float xv[7] = {prev[1], prev[2], prev[3], cur[0], cur[1], cur[2], cur[3]};
    float o[4];
    #pragma unroll
    for (int tt = 0; tt < 4; ++tt) {
        float a = bias;
        #pragma unroll
        for (int k = 0; k < 4; ++k) a = fmaf(xv[tt + k], w[k], a);
        o[tt] = siluf(a);
    }
    *(float4*)((dir ? xcT_b : xcT_f) + ((size_t)r << 10) + t0) = *(float4*)o;
}

// ---------------- K2b: x_dbl GEMM (fp32), both dirs; dt + packed [B|C] tok-major ----------------
__global__ __launch_bounds__(256) void gemm_xdbl(const float* __restrict__ Af,
                                                 const float* __restrict__ Ab,
                                                 const float* __restrict__ Wf,
                                                 const float* __restrict__ Wb,
                                                 float* __restrict__ dtrf,
                                                 float* __restrict__ dtrb,
                                                 float* __restrict__ bcf,
                                                 float* __restrict__ bcb) {
    const int yi = blockIdx.y;
    const float* A = yi ? Ab : Af;
    const float* W = yi ? Wb : Wf;
    float* dtr = yi ? dtrb : dtrf;
    float* bc = yi ? bcb : bcf;
    __shared__ __align__(16) float As[16][68];
    __shared__ __align__(16) float Ws[16][68];
    const int m0 = blockIdx.x * 64;
    const int t = threadIdx.x;
    const int tx = t & 15, ty = t >> 4;
    float acc[4][4] = {};
    const int arow_l = t >> 2;
    const int kq = (t & 3) * 4;
    const int bb_ = m0 >> 10, tt0 = m0 & 1023;
    for (int kt = 0; kt < 25; ++kt) {              // K=392: 24*16+8
        const int k0 = kt << 4;
        {
            int kr = t >> 4, tc = t & 15;
            int kk = k0 + kr;
            float4 v = {0.f, 0.f, 0.f, 0.f};
            if (kk < DI)
                v = *(const float4*)(A + (((size_t)bb_ * DI + kk) << 10) + tt0 + tc * 4);
            *(float4*)&As[kr][tc * 4] = v;
        }
        {
            bool okn = arow_l < XDW;
            const float* wp = W + (size_t)arow_l * DI;
            #pragma unroll
            for (int jj = 0; jj < 4; ++jj) {
                int kk = k0 + kq + jj;
                Ws[kq + jj][arow_l] = (okn && kk < DI) ? wp[kk] : 0.f;
            }
        }
        __syncthreads();
        #pragma unroll
        for (int k = 0; k < 16; ++k) {
            float av[4], wv[4];
            *(float4*)av = *(const float4*)&As[k][ty * 4];
            *(float4*)wv = *(const float4*)&Ws[k][tx * 4];
            #pragma unroll
            for (int i = 0; i < 4; ++i)
                #pragma unroll
                for (int j = 0; j < 4; ++j)
                    acc[i][j] = fmaf(av[i], wv[j], acc[i][j]);
        }
        __syncthreads();
    }
    #pragma unroll
    for (int i = 0; i < 4; ++i) {
        int m = m0 + ty * 4 + i;
        #pragma unroll
        for (int j = 0; j < 4; ++j) {
            int n = tx * 4 + j;
            float v = acc[i][j];
            if (n < DTR) dtr[(size_t)m * DTR + n] = v;
            else if (n < XDW) bc[(size_t)m * 32 + (n - DTR)] = v;
        }
    }
}

// ---------------- K4: delta = softplus(dt @ dt_w^T + dt_b) -> chain-major ----------------
__global__ __launch_bounds__(256) void delta_kernel(
        const float* __restrict__ dtr_f, const float* __restrict__ dtr_b,
        float* __restrict__ dlT_f, float* __restrict__ dlT_b,
        const float* __restrict__ f_dt_w, const float* __restrict__ f_dt_b,
        const float* __restrict__ b_dt_w, const float* __restrict__ b_dt_b) {
    int i = blockIdx.x * 256 + threadIdx.x;       // < 2*DI_SZ
    int dir = i >= (int)DI_SZ;
    int j = dir ? i - (int)DI_SZ : i;             // r*1024 + t
    int r = j >> 10, t = j & 1023;
    int b = r / DI, d = r - (r / DI) * DI;
    size_t tok = ((size_t)b << 10) + t;
    const float* xd = (dir ? dtr_b : dtr_f) + tok * DTR;
    const float* w = (dir ? b_dt_w : f_dt_w) + d * DTR;
    float acc = (dir ? b_dt_b : f_dt_b)[d];
    #pragma unroll
    for (int q = 0; q < DTR; ++q) acc = fmaf(xd[q], w[q], acc);
    float sp = fmaxf(acc, 0.f) + log1pf(__expf(-fabsf(acc)));
    (dir ? dlT_b : dlT_f)[j] = sp;
}

// ---------------- K5: 2-pass chunked scan, 8 chains x 8 chunks x 4 ni (4 states/lane) ----------------
// Measured-best structure (r5/r6 benches) + exp2 fold + prefused silu(z) f16 + owner-lane stores.
__global__ __launch_bounds__(256) void scan_kernel(
        const float* __restrict__ dlT_f, const float* __restrict__ dlT_b,
        const float* __restrict__ xcT_f, const float* __restrict__ xcT_b,
        const float* __restrict__ bc_f,  const float* __restrict__ bc_b,
        const _Float16* __restrict__ zT_f, const _Float16* __restrict__ zT_b,
        _Float16* __restrict__ y16_f,    _Float16* __restrict__ y16_b,
        const float* __restrict__ fA, const float* __restrict__ bA,
        const float* __restrict__ fD, const float* __restrict__ bD) {
    __shared__ float sP[8][8][16];
    __shared__ float sH[8][8][16];
    __shared__ float sI[8][8][16];
    const int tid = threadIdx.x;
    const int ni = tid & 3;
    const int c  = (tid >> 2) & 7;
    const int ch_l = tid >> 5;
    const int chain = blockIdx.x * 8 + ch_l;
    const int dir = chain >= CH;
    const int r = chain - (dir ? CH : 0);
    const int b = r / DI, d = r - (r / DI) * DI;

    const float* dlT = (dir ? dlT_b : dlT_f) + ((size_t)r << 10);
    const float* uT  = (dir ? xcT_b : xcT_f) + ((size_t)r << 10);
    const _Float16* zT = (dir ? zT_b : zT_f) + ((size_t)r << 10);
    const float* BC  = (dir ? bc_b  : bc_f)  + (((size_t)b << 10) * 32);
    _Float16* y16    = (dir ? y16_b : y16_f) + ((size_t)r << 10);
    const float* Al  = (dir ? bA : fA) + d * DS + ni * 4;
    float Av[4];
    #pragma unroll
    for (int i = 0; i < 4; ++i) Av[i] = -__expf(Al[i]) * 1.4426950408889634f;
    const float Dd = (dir ? bD : fD)[d];
    const int t0 = c << 7;

    // ---- phase A: local scan, h0 = 0 ----
    if (c < 7) {
        float h[4] = {0.f, 0.f, 0.f, 0.f};
        float S = 0.f;
        for (int g = 0; g < 32; ++g) {
            const int tg = t0 + g * 4;
            float4 d4 = *(const float4*)(dlT + tg);
            float4 u4 = *(const float4*)(uT + tg);
            float dv[4] = {d4.x, d4.y, d4.z, d4.w};
            float uv[4] = {u4.x, u4.y, u4.z, u4.w};
            #pragma unroll
            for (int tt = 0; tt < 4; ++tt) {
                float4 B4 = *(const float4*)(BC + (size_t)(tg + tt) * 32 + ni * 4);
                float w = dv[tt] * uv[tt];
                S += dv[tt];
                float Bv[4] = {B4.x, B4.y, B4.z, B4.w};
                #pragma unroll
                for (int i = 0; i < 4; ++i)
                    h[i] = fmaf(exp2f(dv[tt] * Av[i]), h[i], w * Bv[i]);
            }
        }
        #pragma unroll
        for (int i = 0; i < 4; ++i) {
            sP[ch_l][c][ni * 4 + i] = exp2f(S * Av[i]);
            sH[ch_l][c][ni * 4 + i] = h[i];
        }
    }
    __syncthreads();

    // ---- phase B: serial combine ----
    if (tid < 128) {
        const int ch = tid >> 4, n = tid & 15;
        float hi = 0.f;
        #pragma unroll
        for (int cc = 0; cc < 8; ++cc) {
            sI[ch][cc][n] = hi;
            if (cc < 7) hi = sH[ch][cc][n] + sP[ch][cc][n] * hi;
        }
    }
    __syncthreads();

    // ---- phase C: rescan with h_init, reduce over n, gate, coalesced store ----
    {
        float h[4];
        #pragma unroll
        for (int i = 0; i < 4; ++i) h[i] = sI[ch_l][c][ni * 4 + i];
        _Float16 ybuf[8] __attribute__((aligned(16)));
        half8 zb;
        for (int g = 0; g < 32; ++g) {
            if ((g & 7) == 0)
                zb = *(const half8*)(zT + t0 + ((g >> 3) << 5) + ni * 8);
            const int tg = t0 + g * 4;
            float4 d4 = *(const float4*)(dlT + tg);
            float4 u4 = *(const float4*)(uT + tg);
            float dv[4] = {d4.x, d4.y, d4.z, d4.w};
            float uv[4] = {u4.x, u4.y, u4.z, u4.w};
            float pq[4];
            #pragma unroll
            for (int tt = 0; tt < 4; ++tt) {
                float4 B4 = *(const float4*)(BC + (size_t)(tg + tt) * 32 + ni * 4);
                float4 C4 = *(const float4*)(BC + (size_t)(tg + tt) * 32 + 16 + ni * 4);
                float w = dv[tt] * uv[tt];
                float Bv[4] = {B4.x, B4.y, B4.z, B4.w};
                float Cv[4] = {C4.x, C4.y, C4.z, C4.w};
                float p = 0.f;
                #pragma unroll
                for (int i = 0; i < 4; ++i) {
                    h[i] = fmaf(exp2f(dv[tt] * Av[i]), h[i], w * Bv[i]);
                    p = fmaf(h[i], Cv[i], p);
                }
                pq[tt] = p;
            }
            #pragma unroll
            for (int tt = 0; tt < 4; ++tt) {
                pq[tt] += __shfl_xor(pq[tt], 1);
                pq[tt] += __shfl_xor(pq[tt], 2);
            }
            if (((g >> 1) & 3) == ni) {
                const int base = (g & 1) * 4;
                #pragma unroll
                for (int tt = 0; tt < 4; ++tt)
                    ybuf[base + tt] =
                        (_Float16)((pq[tt] + Dd * uv[tt]) * (float)zb[base + tt]);
            }
            if ((g & 7) == 7)
                *(half8*)(y16 + t0 + ((g >> 3) << 5) + ni * 8) = *(half8*)ybuf;
        }
    }
}

// ---------------- K5b: transpose y16 chain-major -> tok-major f16 padded 416 ----------------
__global__ __launch_bounds__(256) void transp_y(
        const _Float16* __restrict__ yf, const _Float16* __restrict__ yb,
        _Float16* __restrict__ of, _Float16* __restrict__ ob) {
    __shared__ _Float16 tile[64][72];
    const int dblk = blockIdx.z % 7, dir = blockIdx.z / 7;
    const int b = blockIdx.y, tb = blockIdx.x;
    const _Float16* y = dir ? yb : yf;
    _Float16* o = dir ? ob : of;
    const int d0 = dblk * 64, t0 = tb * 64;
    const int dl = threadIdx.x >> 2, ts = (threadIdx.x & 3) * 16;
    const int d = d0 + dl;
    if (d < DI) {
        const _Float16* src = y + (((size_t)(b * DI + d)) << 10) + t0 + ts;
        *(half8*)&tile[dl][ts] = *(const half8*)src;
        *(half8*)&tile[dl][ts + 8] = *(const half8*)(src + 8);
    } else {
        #pragma unroll
        for (int q = 0; q < 16; ++q) tile[dl][ts + q] = (_Float16)0.f;
    }
    __syncthreads();
    const int tl = threadIdx.x >> 2, ds = (threadIdx.x & 3) * 16;
    if (d0 + ds < KP_OP) {
        _Float16 v[16] __attribute__((aligned(16)));
        #pragma unroll
        for (int q = 0; q < 16; ++q) v[q] = tile[ds + q][tl];
        _Float16* dst = o + ((size_t)((b << 10) + t0 + tl)) * KP_OP + d0 + ds;
        *(half8*)dst = *(half8*)&v[0];
        *(half8*)(dst + 8) = *(half8*)&v[8];
    }
}

// ---------------- K8a: head partials — one wave per token, no atomics ----------------
__global__ __launch_bounds__(256) void final_head(
        const float* __restrict__ fo, const float* __restrict__ bo,
        const float* __restrict__ h, const float* __restrict__ g,
        const float* __restrict__ bb, const float* __restrict__ cls_w,
        float* __restrict__ partial) {
    const int w = threadIdx.x >> 6, lane = threadIdx.x & 63;
    const int t = blockIdx.x * 4 + w;
    const int b = t >> 10, l = t & 1023;
    const float* fp = fo + (size_t)t * DM;
    const float* bp = bo + ((size_t)(b << 10) + (1023 - l)) * DM;
    const float* hp = h + (size_t)t * DM;
    float v[4];
    float s1 = 0.f, s2 = 0.f;
    #pragma unroll
    for (int i = 0; i < 4; ++i) {
        int e = lane + i * 64;
        bool ok = (i < 3) || (lane < 4);
        float vv = ok ? 0.5f * (fp[e] + bp[e]) : 0.f;
        v[i] = vv;
        s1 += vv;
        s2 = fmaf(vv, vv, s2);
    }
    #pragma unroll
    for (int o = 32; o > 0; o >>= 1) {
        s1 += __shfl_xor(s1, o);
        s2 += __shfl_xor(s2, o);
    }
    float mean = s1 * (1.f / DM);
    float var = s2 * (1.f / DM) - mean * mean;
    float inv = rsqrtf(var + 1e-5f);
    float c = 0.f;
    #pragma unroll
    for (int i = 0; i < 4; ++i) {
        int e = lane + i * 64;
        bool ok = (i < 3) || (lane < 4);
        if (ok) {
            float o2 = (v[i] - mean) * inv * g[e] + bb[e];
            o2 = siluf(o2) + hp[e];
            c = fmaf(o2, cls_w[e], c);
        }
    }
    #pragma unroll
    for (int o = 32; o > 0; o >>= 1) c += __shfl_xor(c, o);
    if (lane == 0) partial[t] = c;
}

// ---------------- K8b: reduce 1024 partials per batch -> out ----------------
__global__ __launch_bounds__(256) void head_reduce(const float* __restrict__ partial,
                                                   const float* __restrict__ cls_b,
                                                   float* __restrict__ out) {
    __shared__ float red[4];
    const int b = blockIdx.x;
    const float* p = partial + ((size_t)b << 10);
    float s = 0.f;
    for (int i = threadIdx.x; i < 1024; i += 256) s += p[i];
    s = blk_sum(s, red);
    if (threadIdx.x == 0) out[b] = s * (1.f / 1024.f) + cls_b[0];
}

// ---------------- launch ----------------
extern "C" void kernel_launch(void* const* d_in, const int* in_sizes, int n_in,
                              void* d_out, int out_size, void* d_ws, size_t ws_size,
                              hipStream_t stream) {
    const float* x        = (const float*)d_in[0];
    const float* patch_w  = (const float*)d_in[1];
    const float* patch_b  = (const float*)d_in[2];
    const float* pe_g     = (const float*)d_in[3];
    const float* pe_b     = (const float*)d_in[4];
    const float* blk_g    = (const float*)d_in[5];
    const float* blk_b    = (const float*)d_in[6];
    const float* cls_w    = (const float*)d_in[7];
    const float* cls_b    = (const float*)d_in[8];
    const float* f_in_w   = (const float*)d_in[9];
    const float* f_conv_w = (const float*)d_in[10];
    const float* f_conv_b = (const float*)d_in[11];
    const float* f_xp_w   = (const float*)d_in[12];
    const float* f_dt_w   = (const float*)d_in[13];
    const float* f_dt_b   = (const float*)d_in[14];
    const float* f_A_log  = (const float*)d_in[15];
    const float* f_D      = (const float*)d_in[16];
    const float* f_out_w  = (const float*)d_in[17];
    const float* b_in_w   = (const float*)d_in[18];
    const float* b_conv_w = (const float*)d_in[19];
    const float* b_conv_b = (const float*)d_in[20];
    const float* b_xp_w   = (const float*)d_in[21];
    const float* b_dt_w   = (const float*)d_in[22];
    const float* b_dt_b   = (const float*)d_in[23];
    const float* b_A_log  = (const float*)d_in[24];
    const float* b_D      = (const float*)d_in[25];
    const float* b_out_w  = (const float*)d_in[26];

    float* ws = (float*)d_ws;
    float* out = (float*)d_out;

    float* Hb        = ws + O_H;
    _Float16* H16    = (_Float16*)(ws + O_H16);
    float* XIf       = ws + O_XI_F;
    float* XIb       = ws + O_XI_B;
    _Float16* ZT16f  = (_Float16*)(ws + O_Z_F);   // silu(z)T f16 chain-major
    _Float16* ZT16b  = (_Float16*)(ws + O_Z_B);
    _Float16* YsTf16 = (_Float16*)(ws + O_Z_F);   // after transp: tok-major ys f16
    _Float16* YsTb16 = (_Float16*)(ws + O_Z_B);
    float* XCf       = ws + O_XC_F;               // xcT_f; later head partials
    float* XCb       = ws + O_XC_B;
    float* DTRf      = ws + O_DTR_F;
    float* DTRb      = ws + O_DTR_B;
    float* BCf       = ws + O_BC_F;               // packed [tok][32]
    float* BCb       = ws + O_BC_B;
    _Float16* Xp16   = (_Float16*)(ws + O_YS_F);  // early
    float* TokRaw    = ws + O_YS_B;               // early
    _Float16* Y16f   = (_Float16*)(ws + O_YS_F);  // after scan
    _Float16* Y16b   = (_Float16*)(ws + O_YS_B);
    _Float16* PW16   = (_Float16*)(ws + O_PW16);
    _Float16* FIN16  = (_Float16*)(ws + O_FIN16);
    _Float16* BIN16  = (_Float16*)(ws + O_BIN16);
    _Float16* FOUT16 = (_Float16*)(ws + O_FOUT16);
    _Float16* BOUT16 = (_Float16*)(ws + O_BOUT16);

    // weight conversions (single launch, dst regions contiguous from PW16)
    cvt_all<<<2153, 256, 0, stream>>>(patch_w, f_in_w, b_in_w, f_out_w, b_out_w, PW16);

    // patch embed
    gather_patch<<<(NTOK * 192) / 256, 256, 0, stream>>>(x, Xp16);
    mfma_patch<<<dim3(NTOK / 128, 3), 256, 0, stream>>>(Xp16, PW16, patch_b, TokRaw);
    ln_silu_pos<<<NTOK / 4, 256, 0, stream>>>(TokRaw, pe_g, pe_b, Hb, H16);

    // xz projections -> chain-major (xi fp32, silu(z) f16)
    mfma_xz<<<dim3(NTOK / 128, 7, 4), 256, 0, stream>>>(H16, FIN16, BIN16,
                                                        XIf, ZT16f, XIb, ZT16b);
    // conv + silu
    conv_silu_T<<<2 * CH, 256, 0, stream>>>(XIf, XIb, XCf, XCb,
                                            f_conv_w, f_conv_b, b_conv_w, b_conv_b);
    // x_dbl (fp32) -> dt + packed [B|C] tok-major (merged dirs)
    gemm_xdbl<<<dim3(NTOK / 64, 2), 256, 0, stream>>>(XCf, XCb, f_xp_w, b_xp_w,
                                                      DTRf, DTRb, BCf, BCb);
    // delta -> dlT (overwrites dead xiT)
    delta_kernel<<<(2 * (int)DI_SZ) / 256, 256, 0, stream>>>(
        DTRf, DTRb, XIf, XIb, f_dt_w, f_dt_b, b_dt_w, b_dt_b);
    // 2-pass chunked scan + fused gate -> y16 chain-major
    scan_kernel<<<2 * CH / 8, 256, 0, stream>>>(
        XIf, XIb, XCf, XCb, BCf, BCb, ZT16f, ZT16b, Y16f, Y16b,
        f_A_log, b_A_log, f_D, b_D);
    // transpose -> tok-major f16 (into dead Z regions)
    transp_y<<<dim3(16, 16, 14), 256, 0, stream>>>(Y16f, Y16b, YsTf16, YsTb16);
    // out projections -> fo/bo fp32 tok-major (merged dirs)
    mfma_op<<<dim3(NTOK / 128, 4, 2), 256, 0, stream>>>(YsTf16, YsTb16,
                                                        FOUT16, BOUT16, XIf, XIb);
    // head: partials (into dead XCf region) then reduce
    final_head<<<NTOK / 4, 256, 0, stream>>>(XIf, XIb, Hb, blk_g, blk_b, cls_w, XCf);
    head_reduce<<<B_, 256, 0, stream>>>(XCf, cls_b, out);
}

// Round 11
// 502.999 us; speedup vs baseline: 1.7202x; 1.0378x over previous
//
#include <hip/hip_runtime.h>
#include <cstdint>
#include <cstddef>

// ---------------- problem constants ----------------
constexpr int B_   = 16;
constexpr int L_   = 1024;
constexpr int E_   = 192;
constexpr int DM   = 196;   // D_MODEL
constexpr int DI   = 392;   // D_INNER
constexpr int DS   = 16;    // D_STATE
constexpr int DTR  = 13;    // DT_RANK
constexpr int NTOK = B_ * L_;            // 16384
constexpr int XDW  = DTR + 2 * DS;       // 45
constexpr int CH   = B_ * DI;            // 6272 chains per direction

constexpr int KP_XZ = 224;   // 196 padded to %32
constexpr int KP_OP = 416;   // 392 padded to %32
constexpr int KP_PW = 192;

constexpr size_t HW_SZ = (size_t)NTOK * DM;   // 3,211,264
constexpr size_t DI_SZ = (size_t)NTOK * DI;   // 6,422,528

// ---------------- workspace layout (float offsets, all 16B aligned) ----------------
constexpr size_t O_H     = 0;           // (unused fp32 h slot, kept for layout stability)
constexpr size_t O_H16   = 3211264;     // h f16 (NTOK x 224)
constexpr size_t O_XI_F  = 5046272;     // xiT f16 -> dlT f32 -> fo f16
constexpr size_t O_XI_B  = 11468800;
constexpr size_t O_Z_F   = 17891328;    // silu(z)T f16; later ysT16 tok-major f16
constexpr size_t O_Z_B   = 24313856;
constexpr size_t O_XC_F  = 30736384;    // xcT f32; later head partials
constexpr size_t O_XC_B  = 37158912;
constexpr size_t O_DTR_F = 43581440;    // dt f32 (NTOK x 13)
constexpr size_t O_DTR_B = 43794432;
constexpr size_t O_BC_F  = 44007424;    // [B|C] packed tok-major (NTOK x 32) f32
constexpr size_t O_BC_B  = 44531712;
constexpr size_t O_YS_F  = 45056000;    // early Xp f16; later y16 chain-major
constexpr size_t O_YS_B  = 48267264;    // early tok_raw f32; later y16
constexpr size_t O_PW16  = 51478528;    // patch_w f16 192x192 (36864 f16)
constexpr size_t O_FIN16 = 51496960;    // f_in_w f16 784x224
constexpr size_t O_BIN16 = 51584768;
constexpr size_t O_FOUT16= 51672576;    // f_out_w f16 196x416
constexpr size_t O_BOUT16= 51713344;    // end 51,754,112 (~198 MiB)

typedef _Float16 half8 __attribute__((ext_vector_type(8)));
typedef _Float16 half4v __attribute__((ext_vector_type(4)));
typedef float f32x4v __attribute__((ext_vector_type(4)));

// ---------------- helpers ----------------
__device__ __forceinline__ float siluf(float x) {
    return x / (1.f + __expf(-x));
}

__device__ __forceinline__ float blk_sum(float v, float* red) {
    #pragma unroll
    for (int o = 32; o > 0; o >>= 1) v += __shfl_down(v, o);
    int w = threadIdx.x >> 6;
    __syncthreads();
    if ((threadIdx.x & 63) == 0) red[w] = v;
    __syncthreads();
    return red[0] + red[1] + red[2] + red[3];
}

// ---------------- cvt all 5 weight tensors in one launch ----------------
__global__ __launch_bounds__(256) void cvt_all(const float* __restrict__ pw,
                                               const float* __restrict__ fin,
                                               const float* __restrict__ bin,
                                               const float* __restrict__ fout,
                                               const float* __restrict__ bout,
                                               _Float16* __restrict__ dst) {
    int i = blockIdx.x * 256 + threadIdx.x;       // < 551168
    const float* src; int K, Kp, off;
    if (i < 36864)       { src = pw;   K = 192; Kp = 192; off = i; }
    else if (i < 212480) { src = fin;  K = 196; Kp = 224; off = i - 36864; }
    else if (i < 388096) { src = bin;  K = 196; Kp = 224; off = i - 212480; }
    else if (i < 469632) { src = fout; K = 392; Kp = 416; off = i - 388096; }
    else                 { src = bout; K = 392; Kp = 416; off = i - 469632; }
    int n = off / Kp, k = off - n * Kp;
    dst[i] = (_Float16)(k < K ? src[(size_t)n * K + k] : 0.f);
}

// ---------------- K0: gather patches into (NTOK, 192) f16 ----------------
__global__ __launch_bounds__(256) void gather_patch(const float* __restrict__ x,
                                                    _Float16* __restrict__ Xp) {
    int i = blockIdx.x * 256 + threadIdx.x;
    int tok = i / 192, r = i - tok * 192;
    int c = r >> 6, pq = r & 63, p = pq >> 3, q = pq & 7;
    int b = tok >> 10, l = tok & 1023, hh = l >> 5, wv = l & 31;
    Xp[i] = (_Float16)x[(((size_t)(b * 3 + c) * 256 + hh * 8 + p) << 8) + wv * 8 + q];
}

// ---------------- shared MFMA GEMM core ----------------
// block 256 = 4 waves; tile 128(m) x 64(n); A tok-major f16; optional per-1024 flip.
// MODE 0: C fp32 tok-major (+bias); MODE 2: C f16 chain-major;
// MODE 3: C f16 chain-major with silu; MODE 4: C f16 tok-major (ldc)
template <int MODE>
__device__ __forceinline__ void mfma_core(const _Float16* __restrict__ A,
                                          const _Float16* __restrict__ W,
                                          const float* __restrict__ bias,
                                          void* __restrict__ Cv_,
                                          int N, int Kpad, int ldc,
                                          int flip, int m_blk, int n_blk) {
    const int tid = threadIdx.x;
    const int wv = tid >> 6, lane = tid & 63;
    const int col = lane & 15, quad = lane >> 4;
    const int m_base = m_blk * 128 + wv * 32;
    const int n_base = n_blk * 64;

    int r0 = m_base + col, r1 = m_base + 16 + col;
    if (flip) {
        r0 = (r0 & ~1023) + (1023 - (r0 & 1023));
        r1 = (r1 & ~1023) + (1023 - (r1 & 1023));
    }
    const _Float16* a0p = A + (size_t)r0 * Kpad + quad * 8;
    const _Float16* a1p = A + (size_t)r1 * Kpad + quad * 8;

    const _Float16* bp[4];
    bool bok[4];
    #pragma unroll
    for (int j = 0; j < 4; ++j) {
        int n = n_base + j * 16 + col;
        bok[j] = (n < N);
        bp[j] = W + (size_t)(bok[j] ? n : 0) * Kpad + quad * 8;
    }

    f32x4v acc[2][4];
    #pragma unroll
    for (int i = 0; i < 2; ++i)
        #pragma unroll
        for (int j = 0; j < 4; ++j)
            #pragma unroll
            for (int r = 0; r < 4; ++r) acc[i][j][r] = 0.f;

    half8 bzero;
    #pragma unroll
    for (int q = 0; q < 8; ++q) bzero[q] = (_Float16)0.f;

    for (int k0 = 0; k0 < Kpad; k0 += 32) {
        half8 a0 = *(const half8*)(a0p + k0);
        half8 a1 = *(const half8*)(a1p + k0);
        #pragma unroll
        for (int j = 0; j < 4; ++j) {
            half8 bv = bzero;
            if (bok[j]) bv = *(const half8*)(bp[j] + k0);
            acc[0][j] = __builtin_amdgcn_mfma_f32_16x16x32_f16(a0, bv, acc[0][j], 0, 0, 0);
            acc[1][j] = __builtin_amdgcn_mfma_f32_16x16x32_f16(a1, bv, acc[1][j], 0, 0, 0);
        }
    }

    if (MODE == 0) {
        float* C = (float*)Cv_;
        #pragma unroll
        for (int i = 0; i < 2; ++i) {
            int mrow = m_base + i * 16 + quad * 4;
            #pragma unroll
            for (int j = 0; j < 4; ++j) {
                int n = n_base + j * 16 + col;
                if (n < N) {
                    float bv = bias ? bias[n] : 0.f;
                    #pragma unroll
                    for (int r = 0; r < 4; ++r)
                        C[(size_t)(mrow + r) * ldc + n] = acc[i][j][r] + bv;
                }
            }
        }
    } else if (MODE == 4) {
        _Float16* C = (_Float16*)Cv_;
        #pragma unroll
        for (int i = 0; i < 2; ++i) {
            int mrow = m_base + i * 16 + quad * 4;
            #pragma unroll
            for (int j = 0; j < 4; ++j) {
                int n = n_base + j * 16 + col;
                if (n < N) {
                    #pragma unroll
                    for (int r = 0; r < 4; ++r)
                        C[(size_t)(mrow + r) * ldc + n] = (_Float16)acc[i][j][r];
                }
            }
        }
    } else {
        const int bb = m_base >> 10;
        const int t0 = m_base & 1023;
        #pragma unroll
        for (int i = 0; i < 2; ++i) {
            int tt = t0 + i * 16 + quad * 4;
            #pragma unroll
            for (int j = 0; j < 4; ++j) {
                int n = n_base + j * 16 + col;
                if (n < N) {
                    half4v v;
                    #pragma unroll
                    for (int r = 0; r < 4; ++r) {
                        float xx = acc[i][j][r];
                        if (MODE == 3) xx = xx / (1.f + __expf(-xx));   // silu
                        v[r] = (_Float16)xx;
                    }
                    *(half4v*)((_Float16*)Cv_ + (((size_t)(bb * N + n)) << 10) + tt) = v;
                }
            }
        }
    }
}

// patch embed GEMM (tok-major, bias)
__global__ __launch_bounds__(256) void mfma_patch(const _Float16* __restrict__ A,
                                                  const _Float16* __restrict__ W,
                                                  const float* __restrict__ bias,
                                                  float* __restrict__ C) {
    mfma_core<0>(A, W, bias, C, 192, KP_PW, 192, 0, blockIdx.x, blockIdx.y);
}

// merged xz projections: z = {f_xi(f16), f_z(silu f16), b_xi(f16), b_z(silu f16)}
__global__ __launch_bounds__(256) void mfma_xz(const _Float16* __restrict__ A,
                                               const _Float16* __restrict__ Wf,
                                               const _Float16* __restrict__ Wb,
                                               _Float16* __restrict__ C0, _Float16* __restrict__ C1,
                                               _Float16* __restrict__ C2, _Float16* __restrict__ C3) {
    const int zi = blockIdx.z;
    const _Float16* W = (zi < 2 ? Wf : Wb) + (size_t)(zi & 1) * DI * KP_XZ;
    const int flip = zi >> 1;
    if (zi == 0)      mfma_core<2>(A, W, nullptr, C0, DI, KP_XZ, 0, flip, blockIdx.x, blockIdx.y);
    else if (zi == 1) mfma_core<3>(A, W, nullptr, C1, DI, KP_XZ, 0, flip, blockIdx.x, blockIdx.y);
    else if (zi == 2) mfma_core<2>(A, W, nullptr, C2, DI, KP_XZ, 0, flip, blockIdx.x, blockIdx.y);
    else              mfma_core<3>(A, W, nullptr, C3, DI, KP_XZ, 0, flip, blockIdx.x, blockIdx.y);
}

// merged out-projections (f16 tok-major out): z = {fwd, bwd}
__global__ __launch_bounds__(256) void mfma_op(const _Float16* __restrict__ Af,
                                               const _Float16* __restrict__ Ab,
                                               const _Float16* __restrict__ Wf,
                                               const _Float16* __restrict__ Wb,
                                               _Float16* __restrict__ Cf, _Float16* __restrict__ Cb) {
    const int zi = blockIdx.z;
    mfma_core<4>(zi ? Ab : Af, zi ? Wb : Wf, nullptr, zi ? Cb : Cf,
                 DM, KP_OP, DM, 0, blockIdx.x, blockIdx.y);
}

// ---------------- K1b: LN + SiLU + pos -> h f16 (padded 224); one wave per token ----------------
__global__ __launch_bounds__(256) void ln_silu_pos(const float* __restrict__ tok,
                                                   const float* __restrict__ g,
                                                   const float* __restrict__ bb,
                                                   _Float16* __restrict__ h16) {
    const int w = threadIdx.x >> 6, lane = threadIdx.x & 63;
    const int t = blockIdx.x * 4 + w;
    const float* tp = tok + (size_t)t * E_;
    float v[3];
    float s1 = 0.f, s2 = 0.f;
    #pragma unroll
    for (int i = 0; i < 3; ++i) {
        v[i] = tp[lane + i * 64];
        s1 += v[i];
        s2 = fmaf(v[i], v[i], s2);
    }
    #pragma unroll
    for (int o = 32; o > 0; o >>= 1) {
        s1 += __shfl_xor(s1, o);
        s2 += __shfl_xor(s2, o);
    }
    float mean = s1 * (1.f / E_);
    float var = s2 * (1.f / E_) - mean * mean;
    float inv = rsqrtf(var + 1e-5f);
    _Float16* hq = h16 + (size_t)t * KP_XZ;
    #pragma unroll
    for (int i = 0; i < 3; ++i) {
        int e = lane + i * 64;
        float o = siluf((v[i] - mean) * inv * g[e] + bb[e]);
        hq[e] = (_Float16)o;
    }
    const int l = t & 1023;
    const float scale = 0.19634954084936207f;  // 2*pi/32
    if (lane < 4) {
        float pv = (lane == 0) ? sinf(l * scale)
                 : (lane == 1) ? cosf(l * scale)
                 : (lane == 2) ? sinf((float)(l >> 5) * scale)
                 :               cosf((float)(l >> 5) * scale);
        hq[E_ + lane] = (_Float16)pv;
    } else if (lane < 32) {
        hq[192 + lane] = (_Float16)0.f;   // pad 196..223
    }
}

// ---------------- K2b: x_dbl GEMM with FUSED conv+silu ----------------
// A-staging computes xc = silu(conv(xi)) from f16 xiT and side-stores xc fp32 for the scan.
__global__ __launch_bounds__(256) void gemm_xdbl(const _Float16* __restrict__ xi_f,
                                                 const _Float16* __restrict__ xi_b,
                                                 const float* __restrict__ Wf,
                                                 const float* __restrict__ Wb,
                                                 const float* __restrict__ fcw,
                                                 const float* __restrict__ fcb,
                                                 const float* __restrict__ bcw,
                                                 const float* __restrict__ bcb,
                                                 float* __restrict__ dtrf,
                                                 float* __restrict__ dtrb,
                                                 float* __restrict__ bcf,
                                                 float* __restrict__ bcb2,
                                                 float* __restrict__ xcf,
                                                 float* __restrict__ xcb) {
    const int yi = blockIdx.y;
    const _Float16* xi = yi ? xi_b : xi_f;
    const float* W = yi ? Wb : Wf;
    const float* cw = yi ? bcw : fcw;
    const float* cb = yi ? bcb : fcb;
    float* dtr = yi ? dtrb : dtrf;
    float* bc = yi ? bcb2 : bcf;
    float* xc = yi ? xcb : xcf;
    __shared__ __align__(16) float As[16][68];
    __shared__ __align__(16) float Ws[16][68];
    const int m0 = blockIdx.x * 64;
    const int t = threadIdx.x;
    const int tx = t & 15, ty = t >> 4;
    float acc[4][4] = {};
    const int arow_l = t >> 2;
    const int kq = (t & 3) * 4;
    const int bb_ = m0 >> 10, tt0 = m0 & 1023;
    for (int kt = 0; kt < 25; ++kt) {              // K=392: 24*16+8
        const int k0 = kt << 4;
        {
            int kr = t >> 4, tc = t & 15;
            int kk = k0 + kr;
            float o4[4] = {0.f, 0.f, 0.f, 0.f};
            if (kk < DI) {
                const int tpos = tt0 + tc * 4;
                const _Float16* xp = xi + (((size_t)(bb_ * DI + kk)) << 10) + tpos;
                half4v cur = *(const half4v*)xp;
                half4v prv;
                if (tpos > 0) prv = *(const half4v*)(xp - 4);
                else { prv[0] = prv[1] = prv[2] = prv[3] = (_Float16)0.f; }
                float xw[7] = {(float)prv[1], (float)prv[2], (float)prv[3],
                               (float)cur[0], (float)cur[1], (float)cur[2], (float)cur[3]};
                float4 wv4 = *(const float4*)(cw + kk * 4);
                float wc[4] = {wv4.x, wv4.y, wv4.z, wv4.w};
                float bv = cb[kk];
                #pragma unroll
                for (int j = 0; j < 4; ++j) {
                    float a = bv;
                    #pragma unroll
                    for (int q = 0; q < 4; ++q) a = fmaf(xw[j + q], wc[q], a);
                    o4[j] = siluf(a);
                }
                *(float4*)(xc + (((size_t)(bb_ * DI + kk)) << 10) + tpos) =
                    *(float4*)o4;
            }
            *(float4*)&As[kr][tc * 4] = *(float4*)o4;
        }
        {
            bool okn = arow_l < XDW;
            const float* wp = W + (size_t)arow_l * DI;
            #pragma unroll
            for (int jj = 0; jj < 4; ++jj) {
                int kk = k0 + kq + jj;
                Ws[kq + jj][arow_l] = (okn && kk < DI) ? wp[kk] : 0.f;
            }
        }
        __syncthreads();
        #pragma unroll
        for (int k = 0; k < 16; ++k) {
            float av[4], wv[4];
            *(float4*)av = *(const float4*)&As[k][ty * 4];
            *(float4*)wv = *(const float4*)&Ws[k][tx * 4];
            #pragma unroll
            for (int i = 0; i < 4; ++i)
                #pragma unroll
                for (int j = 0; j < 4; ++j)
                    acc[i][j] = fmaf(av[i], wv[j], acc[i][j]);
        }
        __syncthreads();
    }
    #pragma unroll
    for (int i = 0; i < 4; ++i) {
        int m = m0 + ty * 4 + i;
        #pragma unroll
        for (int j = 0; j < 4; ++j) {
            int n = tx * 4 + j;
            float v = acc[i][j];
            if (n < DTR) dtr[(size_t)m * DTR + n] = v;
            else if (n < XDW) bc[(size_t)m * 32 + (n - DTR)] = v;
        }
    }
}

// ---------------- K4: delta = softplus(dt @ dt_w^T + dt_b) -> chain-major ----------------
__global__ __launch_bounds__(256) void delta_kernel(
        const float* __restrict__ dtr_f, const float* __restrict__ dtr_b,
        float* __restrict__ dlT_f, float* __restrict__ dlT_b,
        const float* __restrict__ f_dt_w, const float* __restrict__ f_dt_b,
        const float* __restrict__ b_dt_w, const float* __restrict__ b_dt_b) {
    int i = blockIdx.x * 256 + threadIdx.x;       // < 2*DI_SZ
    int dir = i >= (int)DI_SZ;
    int j = dir ? i - (int)DI_SZ : i;             // r*1024 + t
    int r = j >> 10, t = j & 1023;
    int b = r / DI, d = r - (r / DI) * DI;
    size_t tok = ((size_t)b << 10) + t;
    const float* xd = (dir ? dtr_b : dtr_f) + tok * DTR;
    const float* w = (dir ? b_dt_w : f_dt_w) + d * DTR;
    float acc = (dir ? b_dt_b : f_dt_b)[d];
    #pragma unroll
    for (int q = 0; q < DTR; ++q) acc = fmaf(xd[q], w[q], acc);
    float sp = fmaxf(acc, 0.f) + log1pf(__expf(-fabsf(acc)));
    (dir ? dlT_b : dlT_f)[j] = sp;
}

// ---------------- K5: 2-pass chunked scan, 8 chains x 8 chunks x 4 ni (4 states/lane) ----------------
__global__ __launch_bounds__(256) void scan_kernel(
        const float* __restrict__ dlT_f, const float* __restrict__ dlT_b,
        const float* __restrict__ xcT_f, const float* __restrict__ xcT_b,
        const float* __restrict__ bc_f,  const float* __restrict__ bc_b,
        const _Float16* __restrict__ zT_f, const _Float16* __restrict__ zT_b,
        _Float16* __restrict__ y16_f,    _Float16* __restrict__ y16_b,
        const float* __restrict__ fA, const float* __restrict__ bA,
        const float* __restrict__ fD, const float* __restrict__ bD) {
    __shared__ float sP[8][8][16];
    __shared__ float sH[8][8][16];
    __shared__ float sI[8][8][16];
    const int tid = threadIdx.x;
    const int ni = tid & 3;
    const int c  = (tid >> 2) & 7;
    const int ch_l = tid >> 5;
    const int chain = blockIdx.x * 8 + ch_l;
    const int dir = chain >= CH;
    const int r = chain - (dir ? CH : 0);
    const int b = r / DI, d = r - (r / DI) * DI;

    const float* dlT = (dir ? dlT_b : dlT_f) + ((size_t)r << 10);
    const float* uT  = (dir ? xcT_b : xcT_f) + ((size_t)r << 10);
    const _Float16* zT = (dir ? zT_b : zT_f) + ((size_t)r << 10);
    const float* BC  = (dir ? bc_b  : bc_f)  + (((size_t)b << 10) * 32);
    _Float16* y16    = (dir ? y16_b : y16_f) + ((size_t)r << 10);
    const float* Al  = (dir ? bA : fA) + d * DS + ni * 4;
    float Av[4];
    #pragma unroll
    for (int i = 0; i < 4; ++i) Av[i] = -__expf(Al[i]) * 1.4426950408889634f;
    const float Dd = (dir ? bD : fD)[d];
    const int t0 = c << 7;

    // ---- phase A: local scan, h0 = 0 ----
    if (c < 7) {
        float h[4] = {0.f, 0.f, 0.f, 0.f};
        float S = 0.f;
        for (int g = 0; g < 32; ++g) {
            const int tg = t0 + g * 4;
            float4 d4 = *(const float4*)(dlT + tg);
            float4 u4 = *(const float4*)(uT + tg);
            float dv[4] = {d4.x, d4.y, d4.z, d4.w};
            float uv[4] = {u4.x, u4.y, u4.z, u4.w};
            #pragma unroll
            for (int tt = 0; tt < 4; ++tt) {
                float4 B4 = *(const float4*)(BC + (size_t)(tg + tt) * 32 + ni * 4);
                float w = dv[tt] * uv[tt];
                S += dv[tt];
                float Bv[4] = {B4.x, B4.y, B4.z, B4.w};
                #pragma unroll
                for (int i = 0; i < 4; ++i)
                    h[i] = fmaf(exp2f(dv[tt] * Av[i]), h[i], w * Bv[i]);
            }
        }
        #pragma unroll
        for (int i = 0; i < 4; ++i) {
            sP[ch_l][c][ni * 4 + i] = exp2f(S * Av[i]);
            sH[ch_l][c][ni * 4 + i] = h[i];
        }
    }
    __syncthreads();

    // ---- phase B: serial combine ----
    if (tid < 128) {
        const int ch = tid >> 4, n = tid & 15;
        float hi = 0.f;
        #pragma unroll
        for (int cc = 0; cc < 8; ++cc) {
            sI[ch][cc][n] = hi;
            if (cc < 7) hi = sH[ch][cc][n] + sP[ch][cc][n] * hi;
        }
    }
    __syncthreads();

    // ---- phase C: rescan with h_init, reduce over n, gate, coalesced store ----
    {
        float h[4];
        #pragma unroll
        for (int i = 0; i < 4; ++i) h[i] = sI[ch_l][c][ni * 4 + i];
        _Float16 ybuf[8] __attribute__((aligned(16)));
        half8 zb;
        for (int g = 0; g < 32; ++g) {
            if ((g & 7) == 0)
                zb = *(const half8*)(zT + t0 + ((g >> 3) << 5) + ni * 8);
            const int tg = t0 + g * 4;
            float4 d4 = *(const float4*)(dlT + tg);
            float4 u4 = *(const float4*)(uT + tg);
            float dv[4] = {d4.x, d4.y, d4.z, d4.w};
            float uv[4] = {u4.x, u4.y, u4.z, u4.w};
            float pq[4];
            #pragma unroll
            for (int tt = 0; tt < 4; ++tt) {
                float4 B4 = *(const float4*)(BC + (size_t)(tg + tt) * 32 + ni * 4);
                float4 C4 = *(const float4*)(BC + (size_t)(tg + tt) * 32 + 16 + ni * 4);
                float w = dv[tt] * uv[tt];
                float Bv[4] = {B4.x, B4.y, B4.z, B4.w};
                float Cv[4] = {C4.x, C4.y, C4.z, C4.w};
                float p = 0.f;
                #pragma unroll
                for (int i = 0; i < 4; ++i) {
                    h[i] = fmaf(exp2f(dv[tt] * Av[i]), h[i], w * Bv[i]);
                    p = fmaf(h[i], Cv[i], p);
                }
                pq[tt] = p;
            }
            #pragma unroll
            for (int tt = 0; tt < 4; ++tt) {
                pq[tt] += __shfl_xor(pq[tt], 1);
                pq[tt] += __shfl_xor(pq[tt], 2);
            }
            if (((g >> 1) & 3) == ni) {
                const int base = (g & 1) * 4;
                #pragma unroll
                for (int tt = 0; tt < 4; ++tt)
                    ybuf[base + tt] =
                        (_Float16)((pq[tt] + Dd * uv[tt]) * (float)zb[base + tt]);
            }
            if ((g & 7) == 7)
                *(half8*)(y16 + t0 + ((g >> 3) << 5) + ni * 8) = *(half8*)ybuf;
        }
    }
}

// ---------------- K5b: transpose y16 chain-major -> tok-major f16 padded 416 ----------------
__global__ __launch_bounds__(256) void transp_y(
        const _Float16* __restrict__ yf, const _Float16* __restrict__ yb,
        _Float16* __restrict__ of, _Float16* __restrict__ ob) {
    __shared__ _Float16 tile[64][72];
    const int dblk = blockIdx.z % 7, dir = blockIdx.z / 7;
    const int b = blockIdx.y, tb = blockIdx.x;
    const _Float16* y = dir ? yb : yf;
    _Float16* o = dir ? ob : of;
    const int d0 = dblk * 64, t0 = tb * 64;
    const int dl = threadIdx.x >> 2, ts = (threadIdx.x & 3) * 16;
    const int d = d0 + dl;
    if (d < DI) {
        const _Float16* src = y + (((size_t)(b * DI + d)) << 10) + t0 + ts;
        *(half8*)&tile[dl][ts] = *(const half8*)src;
        *(half8*)&tile[dl][ts + 8] = *(const half8*)(src + 8);
    } else {
        #pragma unroll
        for (int q = 0; q < 16; ++q) tile[dl][ts + q] = (_Float16)0.f;
    }
    __syncthreads();
    const int tl = threadIdx.x >> 2, ds = (threadIdx.x & 3) * 16;
    if (d0 + ds < KP_OP) {
        _Float16 v[16] __attribute__((aligned(16)));
        #pragma unroll
        for (int q = 0; q < 16; ++q) v[q] = tile[ds + q][tl];
        _Float16* dst = o + ((size_t)((b << 10) + t0 + tl)) * KP_OP + d0 + ds;
        *(half8*)dst = *(half8*)&v[0];
        *(half8*)(dst + 8) = *(half8*)&v[8];
    }
}

// ---------------- K8a: head partials — one wave per token, all-f16 inputs ----------------
__global__ __launch_bounds__(256) void final_head(
        const _Float16* __restrict__ fo, const _Float16* __restrict__ bo,
        const _Float16* __restrict__ h16, const float* __restrict__ g,
        const float* __restrict__ bb, const float* __restrict__ cls_w,
        float* __restrict__ partial) {
    const int w = threadIdx.x >> 6, lane = threadIdx.x & 63;
    const int t = blockIdx.x * 4 + w;
    const int b = t >> 10, l = t & 1023;
    const _Float16* fp = fo + (size_t)t * DM;
    const _Float16* bp = bo + ((size_t)(b << 10) + (1023 - l)) * DM;
    const _Float16* hp = h16 + (size_t)t * KP_XZ;
    float v[4];
    float s1 = 0.f, s2 = 0.f;
    #pragma unroll
    for (int i = 0; i < 4; ++i) {
        int e = lane + i * 64;
        bool ok = (i < 3) || (lane < 4);
        float vv = ok ? 0.5f * ((float)fp[e] + (float)bp[e]) : 0.f;
        v[i] = vv;
        s1 += vv;
        s2 = fmaf(vv, vv, s2);
    }
    #pragma unroll
    for (int o = 32; o > 0; o >>= 1) {
        s1 += __shfl_xor(s1, o);
        s2 += __shfl_xor(s2, o);
    }
    float mean = s1 * (1.f / DM);
    float var = s2 * (1.f / DM) - mean * mean;
    float inv = rsqrtf(var + 1e-5f);
    float c = 0.f;
    #pragma unroll
    for (int i = 0; i < 4; ++i) {
        int e = lane + i * 64;
        bool ok = (i < 3) || (lane < 4);
        if (ok) {
            float o2 = (v[i] - mean) * inv * g[e] + bb[e];
            o2 = siluf(o2) + (float)hp[e];
            c = fmaf(o2, cls_w[e], c);
        }
    }
    #pragma unroll
    for (int o = 32; o > 0; o >>= 1) c += __shfl_xor(c, o);
    if (lane == 0) partial[t] = c;
}

// ---------------- K8b: reduce 1024 partials per batch -> out ----------------
__global__ __launch_bounds__(256) void head_reduce(const float* __restrict__ partial,
                                                   const float* __restrict__ cls_b,
                                                   float* __restrict__ out) {
    __shared__ float red[4];
    const int b = blockIdx.x;
    const float* p = partial + ((size_t)b << 10);
    float s = 0.f;
    for (int i = threadIdx.x; i < 1024; i += 256) s += p[i];
    s = blk_sum(s, red);
    if (threadIdx.x == 0) out[b] = s * (1.f / 1024.f) + cls_b[0];
}

// ---------------- launch ----------------
extern "C" void kernel_launch(void* const* d_in, const int* in_sizes, int n_in,
                              void* d_out, int out_size, void* d_ws, size_t ws_size,
                              hipStream_t stream) {
    const float* x        = (const float*)d_in[0];
    const float* patch_w  = (const float*)d_in[1];
    const float* patch_b  = (const float*)d_in[2];
    const float* pe_g     = (const float*)d_in[3];
    const float* pe_b     = (const float*)d_in[4];
    const float* blk_g    = (const float*)d_in[5];
    const float* blk_b    = (const float*)d_in[6];
    const float* cls_w    = (const float*)d_in[7];
    const float* cls_b    = (const float*)d_in[8];
    const float* f_in_w   = (const float*)d_in[9];
    const float* f_conv_w = (const float*)d_in[10];
    const float* f_conv_b = (const float*)d_in[11];
    const float* f_xp_w   = (const float*)d_in[12];
    const float* f_dt_w   = (const float*)d_in[13];
    const float* f_dt_b   = (const float*)d_in[14];
    const float* f_A_log  = (const float*)d_in[15];
    const float* f_D      = (const float*)d_in[16];
    const float* f_out_w  = (const float*)d_in[17];
    const float* b_in_w   = (const float*)d_in[18];
    const float* b_conv_w = (const float*)d_in[19];
    const float* b_conv_b = (const float*)d_in[20];
    const float* b_xp_w   = (const float*)d_in[21];
    const float* b_dt_w   = (const float*)d_in[22];
    const float* b_dt_b   = (const float*)d_in[23];
    const float* b_A_log  = (const float*)d_in[24];
    const float* b_D      = (const float*)d_in[25];
    const float* b_out_w  = (const float*)d_in[26];

    float* ws = (float*)d_ws;
    float* out = (float*)d_out;

    _Float16* H16    = (_Float16*)(ws + O_H16);
    _Float16* XI16f  = (_Float16*)(ws + O_XI_F);  // xiT f16
    _Float16* XI16b  = (_Float16*)(ws + O_XI_B);
    float* DLf       = ws + O_XI_F;               // dlT fp32 (after xi dead)
    float* DLb       = ws + O_XI_B;
    _Float16* FO16   = (_Float16*)(ws + O_XI_F);  // fo f16 (after dl dead)
    _Float16* BO16   = (_Float16*)(ws + O_XI_B);
    _Float16* ZT16f  = (_Float16*)(ws + O_Z_F);   // silu(z)T f16 chain-major
    _Float16* ZT16b  = (_Float16*)(ws + O_Z_B);
    _Float16* YsTf16 = (_Float16*)(ws + O_Z_F);   // after transp: tok-major ys f16
    _Float16* YsTb16 = (_Float16*)(ws + O_Z_B);
    float* XCf       = ws + O_XC_F;               // xcT fp32; later head partials
    float* XCb       = ws + O_XC_B;
    float* DTRf      = ws + O_DTR_F;
    float* DTRb      = ws + O_DTR_B;
    float* BCf       = ws + O_BC_F;               // packed [tok][32]
    float* BCb       = ws + O_BC_B;
    _Float16* Xp16   = (_Float16*)(ws + O_YS_F);  // early
    float* TokRaw    = ws + O_YS_B;               // early
    _Float16* Y16f   = (_Float16*)(ws + O_YS_F);  // after scan
    _Float16* Y16b   = (_Float16*)(ws + O_YS_B);
    _Float16* PW16   = (_Float16*)(ws + O_PW16);
    _Float16* FIN16  = (_Float16*)(ws + O_FIN16);
    _Float16* BIN16  = (_Float16*)(ws + O_BIN16);
    _Float16* FOUT16 = (_Float16*)(ws + O_FOUT16);
    _Float16* BOUT16 = (_Float16*)(ws + O_BOUT16);

    // weight conversions (single launch, dst regions contiguous from PW16)
    cvt_all<<<2153, 256, 0, stream>>>(patch_w, f_in_w, b_in_w, f_out_w, b_out_w, PW16);

    // patch embed
    gather_patch<<<(NTOK * 192) / 256, 256, 0, stream>>>(x, Xp16);
    mfma_patch<<<dim3(NTOK / 128, 3), 256, 0, stream>>>(Xp16, PW16, patch_b, TokRaw);
    ln_silu_pos<<<NTOK / 4, 256, 0, stream>>>(TokRaw, pe_g, pe_b, H16);

    // xz projections -> chain-major (xi f16, silu(z) f16)
    mfma_xz<<<dim3(NTOK / 128, 7, 4), 256, 0, stream>>>(H16, FIN16, BIN16,
                                                        XI16f, ZT16f, XI16b, ZT16b);
    // fused conv+silu + x_dbl GEMM -> xc fp32, dt, packed [B|C] (merged dirs)
    gemm_xdbl<<<dim3(NTOK / 64, 2), 256, 0, stream>>>(
        XI16f, XI16b, f_xp_w, b_xp_w, f_conv_w, f_conv_b, b_conv_w, b_conv_b,
        DTRf, DTRb, BCf, BCb, XCf, XCb);
    // delta -> dlT fp32 (overwrites dead xiT region)
    delta_kernel<<<(2 * (int)DI_SZ) / 256, 256, 0, stream>>>(
        DTRf, DTRb, DLf, DLb, f_dt_w, f_dt_b, b_dt_w, b_dt_b);
    // 2-pass chunked scan + fused gate -> y16 chain-major
    scan_kernel<<<2 * CH / 8, 256, 0, stream>>>(
        DLf, DLb, XCf, XCb, BCf, BCb, ZT16f, ZT16b, Y16f, Y16b,
        f_A_log, b_A_log, f_D, b_D);
    // transpose -> tok-major f16 (into dead Z regions)
    transp_y<<<dim3(16, 16, 14), 256, 0, stream>>>(Y16f, Y16b, YsTf16, YsTb16);
    // out projections -> fo/bo f16 tok-major (into dead dlT regions, merged dirs)
    mfma_op<<<dim3(NTOK / 128, 4, 2), 256, 0, stream>>>(YsTf16, YsTb16,
                                                        FOUT16, BOUT16, FO16, BO16);
    // head: partials (into dead XCf region) then reduce
    final_head<<<NTOK / 4, 256, 0, stream>>>(FO16, BO16, H16, blk_g, blk_b, cls_w, XCf);
    head_reduce<<<B_, 256, 0, stream>>>(XCf, cls_b, out);
}

// Round 12
// 473.300 us; speedup vs baseline: 1.8281x; 1.0627x over previous
//
#include <hip/hip_runtime.h>
#include <cstdint>
#include <cstddef>

// ---------------- problem constants ----------------
constexpr int B_   = 16;
constexpr int L_   = 1024;
constexpr int E_   = 192;
constexpr int DM   = 196;   // D_MODEL
constexpr int DI   = 392;   // D_INNER
constexpr int DS   = 16;    // D_STATE
constexpr int DTR  = 13;    // DT_RANK
constexpr int NTOK = B_ * L_;            // 16384
constexpr int XDW  = DTR + 2 * DS;       // 45
constexpr int CH   = B_ * DI;            // 6272 chains per direction

constexpr int KP_XZ = 224;   // 196 padded to %32
constexpr int KP_OP = 416;   // 392 padded to %32
constexpr int KP_PW = 192;

constexpr size_t HW_SZ = (size_t)NTOK * DM;
constexpr size_t DI_SZ = (size_t)NTOK * DI;

// ---------------- workspace layout (float offsets, all 16B aligned) ----------------
constexpr size_t O_H     = 0;           // unused
constexpr size_t O_H16   = 3211264;     // h f16 (NTOK x 224)
constexpr size_t O_XI_F  = 5046272;     // xiT f16 -> dlT f32 -> fo f16
constexpr size_t O_XI_B  = 11468800;
constexpr size_t O_Z_F   = 17891328;    // silu(z)T f16; later ysT16 tok-major f16
constexpr size_t O_Z_B   = 24313856;
constexpr size_t O_XC_F  = 30736384;    // xcT f32; later head partials
constexpr size_t O_XC_B  = 37158912;
constexpr size_t O_DTR_F = 43581440;    // dt f32 (NTOK x 13)
constexpr size_t O_DTR_B = 43794432;
constexpr size_t O_BC_F  = 44007424;    // [B|C] packed tok-major (NTOK x 32) f32
constexpr size_t O_BC_B  = 44531712;
constexpr size_t O_YS_F  = 45056000;    // early Xp f16; later y16 chain-major
constexpr size_t O_YS_B  = 48267264;    // early tok_raw f32; later y16
constexpr size_t O_PW16  = 51478528;    // patch_w f16 192x192
constexpr size_t O_FIN16 = 51496960;    // f_in_w f16 784x224
constexpr size_t O_BIN16 = 51584768;
constexpr size_t O_FOUT16= 51672576;    // f_out_w f16 196x416
constexpr size_t O_BOUT16= 51713344;    // end ~198 MiB

typedef _Float16 half8 __attribute__((ext_vector_type(8)));
typedef _Float16 half4v __attribute__((ext_vector_type(4)));
typedef float f32x4v __attribute__((ext_vector_type(4)));

// ---------------- helpers ----------------
__device__ __forceinline__ float siluf(float x) {
    return x / (1.f + __expf(-x));
}
__device__ __forceinline__ float fexp2(float x) {
    return __builtin_amdgcn_exp2f(x);   // bare v_exp_f32
}

__device__ __forceinline__ float blk_sum(float v, float* red) {
    #pragma unroll
    for (int o = 32; o > 0; o >>= 1) v += __shfl_down(v, o);
    int w = threadIdx.x >> 6;
    __syncthreads();
    if ((threadIdx.x & 63) == 0) red[w] = v;
    __syncthreads();
    return red[0] + red[1] + red[2] + red[3];
}

// ---------------- cvt all 5 weight tensors in one launch ----------------
__global__ __launch_bounds__(256) void cvt_all(const float* __restrict__ pw,
                                               const float* __restrict__ fin,
                                               const float* __restrict__ bin,
                                               const float* __restrict__ fout,
                                               const float* __restrict__ bout,
                                               _Float16* __restrict__ dst) {
    int i = blockIdx.x * 256 + threadIdx.x;       // < 551168
    const float* src; int K, Kp, off;
    if (i < 36864)       { src = pw;   K = 192; Kp = 192; off = i; }
    else if (i < 212480) { src = fin;  K = 196; Kp = 224; off = i - 36864; }
    else if (i < 388096) { src = bin;  K = 196; Kp = 224; off = i - 212480; }
    else if (i < 469632) { src = fout; K = 392; Kp = 416; off = i - 388096; }
    else                 { src = bout; K = 392; Kp = 416; off = i - 469632; }
    int n = off / Kp, k = off - n * Kp;
    dst[i] = (_Float16)(k < K ? src[(size_t)n * K + k] : 0.f);
}

// ---------------- K0: gather patches, 8 elems/thread ----------------
__global__ __launch_bounds__(256) void gather_patch(const float* __restrict__ x,
                                                    _Float16* __restrict__ Xp) {
    int i = blockIdx.x * 256 + threadIdx.x;       // < NTOK*24
    int tok = i / 24, r = i - tok * 24;
    int c = r >> 3, p = r & 7;
    int b = tok >> 10, l = tok & 1023, hh = l >> 5, wv = l & 31;
    const float* src = x + (((size_t)(b * 3 + c) * 256 + hh * 8 + p) << 8) + wv * 8;
    float4 v0 = *(const float4*)src;
    float4 v1 = *(const float4*)(src + 4);
    half8 o;
    o[0] = (_Float16)v0.x; o[1] = (_Float16)v0.y; o[2] = (_Float16)v0.z; o[3] = (_Float16)v0.w;
    o[4] = (_Float16)v1.x; o[5] = (_Float16)v1.y; o[6] = (_Float16)v1.z; o[7] = (_Float16)v1.w;
    *(half8*)(Xp + (size_t)tok * 192 + c * 64 + p * 8) = o;
}

// ---------------- shared MFMA GEMM core ----------------
// block 256 = 4 waves; tile 128(m) x 64(n); A tok-major f16; optional per-1024 flip.
// MODE 0: C fp32 tok-major (+bias); MODE 2: C f16 chain-major (LDS-coalesced);
// MODE 3: MODE 2 + silu; MODE 4: C f16 tok-major ldc (LDS-coalesced)
template <int MODE>
__device__ __forceinline__ void mfma_core(const _Float16* __restrict__ A,
                                          const _Float16* __restrict__ W,
                                          const float* __restrict__ bias,
                                          void* __restrict__ Cv_,
                                          int N, int Kpad, int ldc,
                                          int flip, int m_blk, int n_blk) {
    const int tid = threadIdx.x;
    const int wv = tid >> 6, lane = tid & 63;
    const int col = lane & 15, quad = lane >> 4;
    const int m_base = m_blk * 128 + wv * 32;
    const int n_base = n_blk * 64;

    int r0 = m_base + col, r1 = m_base + 16 + col;
    if (flip) {
        r0 = (r0 & ~1023) + (1023 - (r0 & 1023));
        r1 = (r1 & ~1023) + (1023 - (r1 & 1023));
    }
    const _Float16* a0p = A + (size_t)r0 * Kpad + quad * 8;
    const _Float16* a1p = A + (size_t)r1 * Kpad + quad * 8;

    const _Float16* bp[4];
    bool bok[4];
    #pragma unroll
    for (int j = 0; j < 4; ++j) {
        int n = n_base + j * 16 + col;
        bok[j] = (n < N);
        bp[j] = W + (size_t)(bok[j] ? n : 0) * Kpad + quad * 8;
    }

    f32x4v acc[2][4];
    #pragma unroll
    for (int i = 0; i < 2; ++i)
        #pragma unroll
        for (int j = 0; j < 4; ++j)
            #pragma unroll
            for (int r = 0; r < 4; ++r) acc[i][j][r] = 0.f;

    half8 bzero;
    #pragma unroll
    for (int q = 0; q < 8; ++q) bzero[q] = (_Float16)0.f;

    for (int k0 = 0; k0 < Kpad; k0 += 32) {
        half8 a0 = *(const half8*)(a0p + k0);
        half8 a1 = *(const half8*)(a1p + k0);
        #pragma unroll
        for (int j = 0; j < 4; ++j) {
            half8 bv = bzero;
            if (bok[j]) bv = *(const half8*)(bp[j] + k0);
            acc[0][j] = __builtin_amdgcn_mfma_f32_16x16x32_f16(a0, bv, acc[0][j], 0, 0, 0);
            acc[1][j] = __builtin_amdgcn_mfma_f32_16x16x32_f16(a1, bv, acc[1][j], 0, 0, 0);
        }
    }

    if constexpr (MODE == 0) {
        float* C = (float*)Cv_;
        #pragma unroll
        for (int i = 0; i < 2; ++i) {
            int mrow = m_base + i * 16 + quad * 4;
            #pragma unroll
            for (int j = 0; j < 4; ++j) {
                int n = n_base + j * 16 + col;
                if (n < N) {
                    float bv = bias ? bias[n] : 0.f;
                    #pragma unroll
                    for (int r = 0; r < 4; ++r)
                        C[(size_t)(mrow + r) * ldc + n] = acc[i][j][r] + bv;
                }
            }
        }
    } else if constexpr (MODE == 2 || MODE == 3) {
        // chain-major f16: stage [n_loc 64][t_loc 128] pitch 136, then coalesced
        __shared__ _Float16 cst[64 * 136];
        #pragma unroll
        for (int i = 0; i < 2; ++i) {
            int t_loc = wv * 32 + i * 16 + quad * 4;
            #pragma unroll
            for (int j = 0; j < 4; ++j) {
                int n_loc = j * 16 + col;
                half4v v;
                #pragma unroll
                for (int r = 0; r < 4; ++r) {
                    float xx = acc[i][j][r];
                    if (MODE == 3) xx = xx / (1.f + __expf(-xx));
                    v[r] = (_Float16)xx;
                }
                *(half4v*)&cst[n_loc * 136 + t_loc] = v;
            }
        }
        __syncthreads();
        const int n_loc = tid >> 2, chunk = tid & 3;
        const int n = n_base + n_loc;
        if (n < N) {
            const int bb = (m_blk * 128) >> 10;
            const int t0b = (m_blk * 128) & 1023;
            _Float16* dst = (_Float16*)Cv_ + (((size_t)(bb * N + n)) << 10) + t0b + chunk * 32;
            const _Float16* s = &cst[n_loc * 136 + chunk * 32];
            #pragma unroll
            for (int q = 0; q < 4; ++q)
                *(half8*)(dst + q * 8) = *(const half8*)(s + q * 8);
        }
    } else {   // MODE 4: tok-major f16, stage [m_loc 128][n_loc 64] pitch 72
        __shared__ _Float16 cst[128 * 72];
        #pragma unroll
        for (int i = 0; i < 2; ++i) {
            #pragma unroll
            for (int j = 0; j < 4; ++j) {
                int n_loc = j * 16 + col;
                #pragma unroll
                for (int r = 0; r < 4; ++r) {
                    int m_loc = wv * 32 + i * 16 + quad * 4 + r;
                    cst[m_loc * 72 + n_loc] = (_Float16)acc[i][j][r];
                }
            }
        }
        __syncthreads();
        const int m_loc = tid >> 1, half = tid & 1;
        const int m = m_blk * 128 + m_loc;
        _Float16* C = (_Float16*)Cv_;
        const _Float16* s = &cst[m_loc * 72 + half * 32];
        if (n_base + 64 <= N) {
            _Float16* dst = C + (size_t)m * ldc + n_base + half * 32;
            #pragma unroll
            for (int q = 0; q < 4; ++q)
                *(half8*)(dst + q * 8) = *(const half8*)(s + q * 8);
        } else {
            #pragma unroll
            for (int q = 0; q < 32; ++q) {
                int n = n_base + half * 32 + q;
                if (n < N) C[(size_t)m * ldc + n] = s[q];
            }
        }
    }
}

// patch embed GEMM (tok-major fp32, bias)
__global__ __launch_bounds__(256) void mfma_patch(const _Float16* __restrict__ A,
                                                  const _Float16* __restrict__ W,
                                                  const float* __restrict__ bias,
                                                  float* __restrict__ C) {
    mfma_core<0>(A, W, bias, C, 192, KP_PW, 192, 0, blockIdx.x, blockIdx.y);
}

// merged xz projections: z = {f_xi(f16), f_z(silu f16), b_xi(f16), b_z(silu f16)}
__global__ __launch_bounds__(256) void mfma_xz(const _Float16* __restrict__ A,
                                               const _Float16* __restrict__ Wf,
                                               const _Float16* __restrict__ Wb,
                                               _Float16* __restrict__ C0, _Float16* __restrict__ C1,
                                               _Float16* __restrict__ C2, _Float16* __restrict__ C3) {
    const int zi = blockIdx.z;
    const _Float16* W = (zi < 2 ? Wf : Wb) + (size_t)(zi & 1) * DI * KP_XZ;
    const int flip = zi >> 1;
    if (zi == 0)      mfma_core<2>(A, W, nullptr, C0, DI, KP_XZ, 0, flip, blockIdx.x, blockIdx.y);
    else if (zi == 1) mfma_core<3>(A, W, nullptr, C1, DI, KP_XZ, 0, flip, blockIdx.x, blockIdx.y);
    else if (zi == 2) mfma_core<2>(A, W, nullptr, C2, DI, KP_XZ, 0, flip, blockIdx.x, blockIdx.y);
    else              mfma_core<3>(A, W, nullptr, C3, DI, KP_XZ, 0, flip, blockIdx.x, blockIdx.y);
}

// merged out-projections (f16 tok-major out): z = {fwd, bwd}
__global__ __launch_bounds__(256) void mfma_op(const _Float16* __restrict__ Af,
                                               const _Float16* __restrict__ Ab,
                                               const _Float16* __restrict__ Wf,
                                               const _Float16* __restrict__ Wb,
                                               _Float16* __restrict__ Cf, _Float16* __restrict__ Cb) {
    const int zi = blockIdx.z;
    mfma_core<4>(zi ? Ab : Af, zi ? Wb : Wf, nullptr, zi ? Cb : Cf,
                 DM, KP_OP, DM, 0, blockIdx.x, blockIdx.y);
}

// ---------------- K1b: LN + SiLU + pos -> h f16 (padded 224); one wave per token ----------------
__global__ __launch_bounds__(256) void ln_silu_pos(const float* __restrict__ tok,
                                                   const float* __restrict__ g,
                                                   const float* __restrict__ bb,
                                                   _Float16* __restrict__ h16) {
    const int w = threadIdx.x >> 6, lane = threadIdx.x & 63;
    const int t = blockIdx.x * 4 + w;
    const float* tp = tok + (size_t)t * E_;
    float v[3];
    float s1 = 0.f, s2 = 0.f;
    #pragma unroll
    for (int i = 0; i < 3; ++i) {
        v[i] = tp[lane + i * 64];
        s1 += v[i];
        s2 = fmaf(v[i], v[i], s2);
    }
    #pragma unroll
    for (int o = 32; o > 0; o >>= 1) {
        s1 += __shfl_xor(s1, o);
        s2 += __shfl_xor(s2, o);
    }
    float mean = s1 * (1.f / E_);
    float var = s2 * (1.f / E_) - mean * mean;
    float inv = rsqrtf(var + 1e-5f);
    _Float16* hq = h16 + (size_t)t * KP_XZ;
    #pragma unroll
    for (int i = 0; i < 3; ++i) {
        int e = lane + i * 64;
        float o = siluf((v[i] - mean) * inv * g[e] + bb[e]);
        hq[e] = (_Float16)o;
    }
    const int l = t & 1023;
    const float scale = 0.19634954084936207f;  // 2*pi/32
    if (lane < 4) {
        float pv = (lane == 0) ? sinf(l * scale)
                 : (lane == 1) ? cosf(l * scale)
                 : (lane == 2) ? sinf((float)(l >> 5) * scale)
                 :               cosf((float)(l >> 5) * scale);
        hq[E_ + lane] = (_Float16)pv;
    } else if (lane < 32) {
        hq[192 + lane] = (_Float16)0.f;
    }
}

// ---------------- K2b: x_dbl GEMM with FUSED conv+silu ----------------
__global__ __launch_bounds__(256) void gemm_xdbl(const _Float16* __restrict__ xi_f,
                                                 const _Float16* __restrict__ xi_b,
                                                 const float* __restrict__ Wf,
                                                 const float* __restrict__ Wb,
                                                 const float* __restrict__ fcw,
                                                 const float* __restrict__ fcb,
                                                 const float* __restrict__ bcw,
                                                 const float* __restrict__ bcb,
                                                 float* __restrict__ dtrf,
                                                 float* __restrict__ dtrb,
                                                 float* __restrict__ bcf,
                                                 float* __restrict__ bcb2,
                                                 float* __restrict__ xcf,
                                                 float* __restrict__ xcb) {
    const int yi = blockIdx.y;
    const _Float16* xi = yi ? xi_b : xi_f;
    const float* W = yi ? Wb : Wf;
    const float* cw = yi ? bcw : fcw;
    const float* cb = yi ? bcb : fcb;
    float* dtr = yi ? dtrb : dtrf;
    float* bc = yi ? bcb2 : bcf;
    float* xc = yi ? xcb : xcf;
    __shared__ __align__(16) float As[16][68];
    __shared__ __align__(16) float Ws[16][68];
    const int m0 = blockIdx.x * 64;
    const int t = threadIdx.x;
    const int tx = t & 15, ty = t >> 4;
    float acc[4][4] = {};
    const int arow_l = t >> 2;
    const int kq = (t & 3) * 4;
    const int bb_ = m0 >> 10, tt0 = m0 & 1023;
    for (int kt = 0; kt < 25; ++kt) {              // K=392: 24*16+8
        const int k0 = kt << 4;
        {
            int kr = t >> 4, tc = t & 15;
            int kk = k0 + kr;
            float o4[4] = {0.f, 0.f, 0.f, 0.f};
            if (kk < DI) {
                const int tpos = tt0 + tc * 4;
                const _Float16* xp = xi + (((size_t)(bb_ * DI + kk)) << 10) + tpos;
                half4v cur = *(const half4v*)xp;
                half4v prv;
                if (tpos > 0) prv = *(const half4v*)(xp - 4);
                else { prv[0] = prv[1] = prv[2] = prv[3] = (_Float16)0.f; }
                float xw[7] = {(float)prv[1], (float)prv[2], (float)prv[3],
                               (float)cur[0], (float)cur[1], (float)cur[2], (float)cur[3]};
                float4 wv4 = *(const float4*)(cw + kk * 4);
                float wc[4] = {wv4.x, wv4.y, wv4.z, wv4.w};
                float bv = cb[kk];
                #pragma unroll
                for (int j = 0; j < 4; ++j) {
                    float a = bv;
                    #pragma unroll
                    for (int q = 0; q < 4; ++q) a = fmaf(xw[j + q], wc[q], a);
                    o4[j] = siluf(a);
                }
                *(float4*)(xc + (((size_t)(bb_ * DI + kk)) << 10) + tpos) =
                    *(float4*)o4;
            }
            *(float4*)&As[kr][tc * 4] = *(float4*)o4;
        }
        {
            bool okn = arow_l < XDW;
            const float* wp = W + (size_t)arow_l * DI;
            #pragma unroll
            for (int jj = 0; jj < 4; ++jj) {
                int kk = k0 + kq + jj;
                Ws[kq + jj][arow_l] = (okn && kk < DI) ? wp[kk] : 0.f;
            }
        }
        __syncthreads();
        #pragma unroll
        for (int k = 0; k < 16; ++k) {
            float av[4], wv[4];
            *(float4*)av = *(const float4*)&As[k][ty * 4];
            *(float4*)wv = *(const float4*)&Ws[k][tx * 4];
            #pragma unroll
            for (int i = 0; i < 4; ++i)
                #pragma unroll
                for (int j = 0; j < 4; ++j)
                    acc[i][j] = fmaf(av[i], wv[j], acc[i][j]);
        }
        __syncthreads();
    }
    #pragma unroll
    for (int i = 0; i < 4; ++i) {
        int m = m0 + ty * 4 + i;
        #pragma unroll
        for (int j = 0; j < 4; ++j) {
            int n = tx * 4 + j;
            float v = acc[i][j];
            if (n < DTR) dtr[(size_t)m * DTR + n] = v;
            else if (n < XDW) bc[(size_t)m * 32 + (n - DTR)] = v;
        }
    }
}

// ---------------- K4: delta = softplus(dt @ dt_w^T + dt_b) -> chain-major ----------------
__global__ __launch_bounds__(256) void delta_kernel(
        const float* __restrict__ dtr_f, const float* __restrict__ dtr_b,
        float* __restrict__ dlT_f, float* __restrict__ dlT_b,
        const float* __restrict__ f_dt_w, const float* __restrict__ f_dt_b,
        const float* __restrict__ b_dt_w, const float* __restrict__ b_dt_b) {
    int i = blockIdx.x * 256 + threadIdx.x;
    int dir = i >= (int)DI_SZ;
    int j = dir ? i - (int)DI_SZ : i;             // r*1024 + t
    int r = j >> 10, t = j & 1023;
    int b = r / DI, d = r - (r / DI) * DI;
    size_t tok = ((size_t)b << 10) + t;
    const float* xd = (dir ? dtr_b : dtr_f) + tok * DTR;
    const float* w = (dir ? b_dt_w : f_dt_w) + d * DTR;
    float acc = (dir ? b_dt_b : f_dt_b)[d];
    #pragma unroll
    for (int q = 0; q < DTR; ++q) acc = fmaf(xd[q], w[q], acc);
    float sp = fmaxf(acc, 0.f) + log1pf(__expf(-fabsf(acc)));
    (dir ? dlT_b : dlT_f)[j] = sp;
}

// ---------------- K5: 2-pass chunked scan, 8 chains x 8 chunks x 4 ni (4 states/lane) ----------------
__global__ __launch_bounds__(256) void scan_kernel(
        const float* __restrict__ dlT_f, const float* __restrict__ dlT_b,
        const float* __restrict__ xcT_f, const float* __restrict__ xcT_b,
        const float* __restrict__ bc_f,  const float* __restrict__ bc_b,
        const _Float16* __restrict__ zT_f, const _Float16* __restrict__ zT_b,
        _Float16* __restrict__ y16_f,    _Float16* __restrict__ y16_b,
        const float* __restrict__ fA, const float* __restrict__ bA,
        const float* __restrict__ fD, const float* __restrict__ bD) {
    __shared__ float sP[8][8][16];
    __shared__ float sH[8][8][16];
    __shared__ float sI[8][8][16];
    const int tid = threadIdx.x;
    const int ni = tid & 3;
    const int c  = (tid >> 2) & 7;
    const int ch_l = tid >> 5;
    const int chain = blockIdx.x * 8 + ch_l;
    const int dir = chain >= CH;
    const int r = chain - (dir ? CH : 0);
    const int b = r / DI, d = r - (r / DI) * DI;

    const float* dlT = (dir ? dlT_b : dlT_f) + ((size_t)r << 10);
    const float* uT  = (dir ? xcT_b : xcT_f) + ((size_t)r << 10);
    const _Float16* zT = (dir ? zT_b : zT_f) + ((size_t)r << 10);
    const float* BC  = (dir ? bc_b  : bc_f)  + (((size_t)b << 10) * 32);
    _Float16* y16    = (dir ? y16_b : y16_f) + ((size_t)r << 10);
    const float* Al  = (dir ? bA : fA) + d * DS + ni * 4;
    float Av[4];
    #pragma unroll
    for (int i = 0; i < 4; ++i) Av[i] = -__expf(Al[i]) * 1.4426950408889634f;
    const float Dd = (dir ? bD : fD)[d];
    const int t0 = c << 7;

    // ---- phase A: local scan, h0 = 0 ----
    if (c < 7) {
        float h[4] = {0.f, 0.f, 0.f, 0.f};
        float S = 0.f;
        const float* bcp = BC + t0 * 32 + ni * 4;
        const float* dp = dlT + t0;
        const float* up = uT + t0;
        for (int g = 0; g < 32; ++g) {
            float4 d4 = *(const float4*)(dp + g * 4);
            float4 u4 = *(const float4*)(up + g * 4);
            float dv[4] = {d4.x, d4.y, d4.z, d4.w};
            float uv[4] = {u4.x, u4.y, u4.z, u4.w};
            #pragma unroll
            for (int tt = 0; tt < 4; ++tt) {
                float4 B4 = *(const float4*)(bcp + tt * 32);
                float w = dv[tt] * uv[tt];
                S += dv[tt];
                float Bv[4] = {B4.x, B4.y, B4.z, B4.w};
                #pragma unroll
                for (int i = 0; i < 4; ++i)
                    h[i] = fmaf(fexp2(dv[tt] * Av[i]), h[i], w * Bv[i]);
            }
            bcp += 128;
        }
        #pragma unroll
        for (int i = 0; i < 4; ++i) {
            sP[ch_l][c][ni * 4 + i] = fexp2(S * Av[i]);
            sH[ch_l][c][ni * 4 + i] = h[i];
        }
    }
    __syncthreads();

    // ---- phase B: serial combine ----
    if (tid < 128) {
        const int ch = tid >> 4, n = tid & 15;
        float hi = 0.f;
        #pragma unroll
        for (int cc = 0; cc < 8; ++cc) {
            sI[ch][cc][n] = hi;
            if (cc < 7) hi = sH[ch][cc][n] + sP[ch][cc][n] * hi;
        }
    }
    __syncthreads();

    // ---- phase C: rescan with h_init, reduce over n, gate, coalesced store ----
    {
        float h[4];
        #pragma unroll
        for (int i = 0; i < 4; ++i) h[i] = sI[ch_l][c][ni * 4 + i];
        _Float16 ybuf[8] __attribute__((aligned(16)));
        half8 zb;
        const float* bcp = BC + t0 * 32 + ni * 4;
        const float* dp = dlT + t0;
        const float* up = uT + t0;
        for (int g = 0; g < 32; ++g) {
            if ((g & 7) == 0)
                zb = *(const half8*)(zT + t0 + ((g >> 3) << 5) + ni * 8);
            float4 d4 = *(const float4*)(dp + g * 4);
            float4 u4 = *(const float4*)(up + g * 4);
            float dv[4] = {d4.x, d4.y, d4.z, d4.w};
            float uv[4] = {u4.x, u4.y, u4.z, u4.w};
            float pq[4];
            #pragma unroll
            for (int tt = 0; tt < 4; ++tt) {
                float4 B4 = *(const float4*)(bcp + tt * 32);
                float4 C4 = *(const float4*)(bcp + tt * 32 + 16);
                float w = dv[tt] * uv[tt];
                float Bv[4] = {B4.x, B4.y, B4.z, B4.w};
                float Cv[4] = {C4.x, C4.y, C4.z, C4.w};
                float p = 0.f;
                #pragma unroll
                for (int i = 0; i < 4; ++i) {
                    h[i] = fmaf(fexp2(dv[tt] * Av[i]), h[i], w * Bv[i]);
                    p = fmaf(h[i], Cv[i], p);
                }
                pq[tt] = p;
            }
            bcp += 128;
            #pragma unroll
            for (int tt = 0; tt < 4; ++tt) {
                pq[tt] += __shfl_xor(pq[tt], 1);
                pq[tt] += __shfl_xor(pq[tt], 2);
            }
            if (((g >> 1) & 3) == ni) {
                const int base = (g & 1) * 4;
                #pragma unroll
                for (int tt = 0; tt < 4; ++tt)
                    ybuf[base + tt] =
                        (_Float16)((pq[tt] + Dd * uv[tt]) * (float)zb[base + tt]);
            }
            if ((g & 7) == 7)
                *(half8*)(y16 + t0 + ((g >> 3) << 5) + ni * 8) = *(half8*)ybuf;
        }
    }
}

// ---------------- K5b: transpose y16 chain-major -> tok-major f16 padded 416 ----------------
__global__ __launch_bounds__(256) void transp_y(
        const _Float16* __restrict__ yf, const _Float16* __restrict__ yb,
        _Float16* __restrict__ of, _Float16* __restrict__ ob) {
    __shared__ _Float16 tile[64][72];
    const int dblk = blockIdx.z % 7, dir = blockIdx.z / 7;
    const int b = blockIdx.y, tb = blockIdx.x;
    const _Float16* y = dir ? yb : yf;
    _Float16* o = dir ? ob : of;
    const int d0 = dblk * 64, t0 = tb * 64;
    const int dl = threadIdx.x >> 2, ts = (threadIdx.x & 3) * 16;
    const int d = d0 + dl;
    if (d < DI) {
        const _Float16* src = y + (((size_t)(b * DI + d)) << 10) + t0 + ts;
        *(half8*)&tile[dl][ts] = *(const half8*)src;
        *(half8*)&tile[dl][ts + 8] = *(const half8*)(src + 8);
    } else {
        #pragma unroll
        for (int q = 0; q < 16; ++q) tile[dl][ts + q] = (_Float16)0.f;
    }
    __syncthreads();
    const int tl = threadIdx.x >> 2, ds = (threadIdx.x & 3) * 16;
    if (d0 + ds < KP_OP) {
        _Float16 v[16] __attribute__((aligned(16)));
        #pragma unroll
        for (int q = 0; q < 16; ++q) v[q] = tile[ds + q][tl];
        _Float16* dst = o + ((size_t)((b << 10) + t0 + tl)) * KP_OP + d0 + ds;
        *(half8*)dst = *(half8*)&v[0];
        *(half8*)(dst + 8) = *(half8*)&v[8];
    }
}

// ---------------- K8a: head partials — one wave per token, all-f16 inputs ----------------
__global__ __launch_bounds__(256) void final_head(
        const _Float16* __restrict__ fo, const _Float16* __restrict__ bo,
        const _Float16* __restrict__ h16, const float* __restrict__ g,
        const float* __restrict__ bb, const float* __restrict__ cls_w,
        float* __restrict__ partial) {
    const int w = threadIdx.x >> 6, lane = threadIdx.x & 63;
    const int t = blockIdx.x * 4 + w;
    const int b = t >> 10, l = t & 1023;
    const _Float16* fp = fo + (size_t)t * DM;
    const _Float16* bp = bo + ((size_t)(b << 10) + (1023 - l)) * DM;
    const _Float16* hp = h16 + (size_t)t * KP_XZ;
    float v[4];
    float s1 = 0.f, s2 = 0.f;
    #pragma unroll
    for (int i = 0; i < 4; ++i) {
        int e = lane + i * 64;
        bool ok = (i < 3) || (lane < 4);
        float vv = ok ? 0.5f * ((float)fp[e] + (float)bp[e]) : 0.f;
        v[i] = vv;
        s1 += vv;
        s2 = fmaf(vv, vv, s2);
    }
    #pragma unroll
    for (int o = 32; o > 0; o >>= 1) {
        s1 += __shfl_xor(s1, o);
        s2 += __shfl_xor(s2, o);
    }
    float mean = s1 * (1.f / DM);
    float var = s2 * (1.f / DM) - mean * mean;
    float inv = rsqrtf(var + 1e-5f);
    float c = 0.f;
    #pragma unroll
    for (int i = 0; i < 4; ++i) {
        int e = lane + i * 64;
        bool ok = (i < 3) || (lane < 4);
        if (ok) {
            float o2 = (v[i] - mean) * inv * g[e] + bb[e];
            o2 = siluf(o2) + (float)hp[e];
            c = fmaf(o2, cls_w[e], c);
        }
    }
    #pragma unroll
    for (int o = 32; o > 0; o >>= 1) c += __shfl_xor(c, o);
    if (lane == 0) partial[t] = c;
}

// ---------------- K8b: reduce 1024 partials per batch -> out ----------------
__global__ __launch_bounds__(256) void head_reduce(const float* __restrict__ partial,
                                                   const float* __restrict__ cls_b,
                                                   float* __restrict__ out) {
    __shared__ float red[4];
    const int b = blockIdx.x;
    const float* p = partial + ((size_t)b << 10);
    float s = 0.f;
    for (int i = threadIdx.x; i < 1024; i += 256) s += p[i];
    s = blk_sum(s, red);
    if (threadIdx.x == 0) out[b] = s * (1.f / 1024.f) + cls_b[0];
}

// ---------------- launch ----------------
extern "C" void kernel_launch(void* const* d_in, const int* in_sizes, int n_in,
                              void* d_out, int out_size, void* d_ws, size_t ws_size,
                              hipStream_t stream) {
    const float* x        = (const float*)d_in[0];
    const float* patch_w  = (const float*)d_in[1];
    const float* patch_b  = (const float*)d_in[2];
    const float* pe_g     = (const float*)d_in[3];
    const float* pe_b     = (const float*)d_in[4];
    const float* blk_g    = (const float*)d_in[5];
    const float* blk_b    = (const float*)d_in[6];
    const float* cls_w    = (const float*)d_in[7];
    const float* cls_b    = (const float*)d_in[8];
    const float* f_in_w   = (const float*)d_in[9];
    const float* f_conv_w = (const float*)d_in[10];
    const float* f_conv_b = (const float*)d_in[11];
    const float* f_xp_w   = (const float*)d_in[12];
    const float* f_dt_w   = (const float*)d_in[13];
    const float* f_dt_b   = (const float*)d_in[14];
    const float* f_A_log  = (const float*)d_in[15];
    const float* f_D      = (const float*)d_in[16];
    const float* f_out_w  = (const float*)d_in[17];
    const float* b_in_w   = (const float*)d_in[18];
    const float* b_conv_w = (const float*)d_in[19];
    const float* b_conv_b = (const float*)d_in[20];
    const float* b_xp_w   = (const float*)d_in[21];
    const float* b_dt_w   = (const float*)d_in[22];
    const float* b_dt_b   = (const float*)d_in[23];
    const float* b_A_log  = (const float*)d_in[24];
    const float* b_D      = (const float*)d_in[25];
    const float* b_out_w  = (const float*)d_in[26];

    float* ws = (float*)d_ws;
    float* out = (float*)d_out;

    _Float16* H16    = (_Float16*)(ws + O_H16);
    _Float16* XI16f  = (_Float16*)(ws + O_XI_F);
    _Float16* XI16b  = (_Float16*)(ws + O_XI_B);
    float* DLf       = ws + O_XI_F;
    float* DLb       = ws + O_XI_B;
    _Float16* FO16   = (_Float16*)(ws + O_XI_F);
    _Float16* BO16   = (_Float16*)(ws + O_XI_B);
    _Float16* ZT16f  = (_Float16*)(ws + O_Z_F);
    _Float16* ZT16b  = (_Float16*)(ws + O_Z_B);
    _Float16* YsTf16 = (_Float16*)(ws + O_Z_F);
    _Float16* YsTb16 = (_Float16*)(ws + O_Z_B);
    float* XCf       = ws + O_XC_F;
    float* XCb       = ws + O_XC_B;
    float* DTRf      = ws + O_DTR_F;
    float* DTRb      = ws + O_DTR_B;
    float* BCf       = ws + O_BC_F;
    float* BCb       = ws + O_BC_B;
    _Float16* Xp16   = (_Float16*)(ws + O_YS_F);
    float* TokRaw    = ws + O_YS_B;
    _Float16* Y16f   = (_Float16*)(ws + O_YS_F);
    _Float16* Y16b   = (_Float16*)(ws + O_YS_B);
    _Float16* PW16   = (_Float16*)(ws + O_PW16);
    _Float16* FIN16  = (_Float16*)(ws + O_FIN16);
    _Float16* BIN16  = (_Float16*)(ws + O_BIN16);
    _Float16* FOUT16 = (_Float16*)(ws + O_FOUT16);
    _Float16* BOUT16 = (_Float16*)(ws + O_BOUT16);

    cvt_all<<<2153, 256, 0, stream>>>(patch_w, f_in_w, b_in_w, f_out_w, b_out_w, PW16);

    gather_patch<<<(NTOK * 24) / 256, 256, 0, stream>>>(x, Xp16);
    mfma_patch<<<dim3(NTOK / 128, 3), 256, 0, stream>>>(Xp16, PW16, patch_b, TokRaw);
    ln_silu_pos<<<NTOK / 4, 256, 0, stream>>>(TokRaw, pe_g, pe_b, H16);

    mfma_xz<<<dim3(NTOK / 128, 7, 4), 256, 0, stream>>>(H16, FIN16, BIN16,
                                                        XI16f, ZT16f, XI16b, ZT16b);
    gemm_xdbl<<<dim3(NTOK / 64, 2), 256, 0, stream>>>(
        XI16f, XI16b, f_xp_w, b_xp_w, f_conv_w, f_conv_b, b_conv_w, b_conv_b,
        DTRf, DTRb, BCf, BCb, XCf, XCb);
    delta_kernel<<<(2 * (int)DI_SZ) / 256, 256, 0, stream>>>(
        DTRf, DTRb, DLf, DLb, f_dt_w, f_dt_b, b_dt_w, b_dt_b);
    scan_kernel<<<2 * CH / 8, 256, 0, stream>>>(
        DLf, DLb, XCf, XCb, BCf, BCb, ZT16f, ZT16b, Y16f, Y16b,
        f_A_log, b_A_log, f_D, b_D);
    transp_y<<<dim3(16, 16, 14), 256, 0, stream>>>(Y16f, Y16b, YsTf16, YsTb16);
    mfma_op<<<dim3(NTOK / 128, 4, 2), 256, 0, stream>>>(YsTf16, YsTb16,
                                                        FOUT16, BOUT16, FO16, BO16);
    final_head<<<NTOK / 4, 256, 0, stream>>>(FO16, BO16, H16, blk_g, blk_b, cls_w, XCf);
    head_reduce<<<B_, 256, 0, stream>>>(XCf, cls_b, out);
}